// Round 1
// baseline (543.089 us; speedup 1.0000x reference)
//
#include <hip/hip_runtime.h>
#include <hip/hip_bf16.h>
#include <stdint.h>

#define B_SZ   2
#define S_LEN  2048
#define DMODEL 2048
#define NH     16
#define DHD    128

typedef __attribute__((ext_vector_type(8))) __bf16 bf16x8;
typedef __attribute__((ext_vector_type(4))) float  f32x4;
typedef __attribute__((ext_vector_type(4))) float  float4v;
typedef __attribute__((ext_vector_type(8))) unsigned short ushort8;
typedef __attribute__((ext_vector_type(4))) unsigned short ushort4v;

__device__ __forceinline__ unsigned short f2bf(float f) {
  unsigned int u = __float_as_uint(f);
  unsigned int r = (u + 0x7fffu + ((u >> 16) & 1u)) >> 16;
  return (unsigned short)r;
}

__device__ __forceinline__ void async_cp16(void* lds, const void* g) {
  __builtin_amdgcn_global_load_lds(
      (const __attribute__((address_space(1))) void*)g,
      (__attribute__((address_space(3))) void*)lds, 16, 0, 0);
}

// ---------------- elementwise cast x -> bf16 ----------------
__global__ __launch_bounds__(256) void k_cast_bf16(const float* __restrict__ in,
                                                   unsigned short* __restrict__ out,
                                                   int n4) {
  int i = blockIdx.x * 256 + threadIdx.x;
  if (i >= n4) return;
  float4v v = ((const float4v*)in)[i];
  ushort4v o;
  o[0] = f2bf(v[0]); o[1] = f2bf(v[1]); o[2] = f2bf(v[2]); o[3] = f2bf(v[3]);
  ((ushort4v*)out)[i] = o;
}

// ---------------- transpose + cast W[K][N] -> WT[N][K] bf16 ----------------
__global__ __launch_bounds__(256) void k_transpose_cast(const float* __restrict__ W,
                                                        unsigned short* __restrict__ WT) {
  __shared__ unsigned short tile[64 * 72];
  const int n0 = blockIdx.x * 64;
  const int k0 = blockIdx.y * 64;
  const int t = threadIdx.x;
#pragma unroll
  for (int i = 0; i < 4; ++i) {
    int c = t + 256 * i;
    int r = c >> 4, c4 = c & 15;
    float4v v = *(const float4v*)(W + (size_t)(k0 + r) * DMODEL + n0 + c4 * 4);
    ushort4v o;
    o[0] = f2bf(v[0]); o[1] = f2bf(v[1]); o[2] = f2bf(v[2]); o[3] = f2bf(v[3]);
    *(ushort4v*)(&tile[r * 72 + c4 * 4]) = o;
  }
  __syncthreads();
#pragma unroll
  for (int i = 0; i < 2; ++i) {
    int c = t + 256 * i;
    int n = c >> 3, k8 = c & 7;
    ushort8 o;
#pragma unroll
    for (int j = 0; j < 8; ++j) o[j] = tile[(k8 * 8 + j) * 72 + n];
    *(ushort8*)(WT + (size_t)(n0 + n) * DMODEL + k0 + k8 * 8) = o;
  }
}

// ---------------- rope cos/sin table [S][64] ----------------
__global__ __launch_bounds__(256) void k_rope_table(float* __restrict__ cosT,
                                                    float* __restrict__ sinT) {
  int i = blockIdx.x * 256 + threadIdx.x;  // < S_LEN*64
  int s = i >> 6, dj = i & 63;
  float e = __expf(-9.210340371976184f * (float)dj * (1.0f / 64.0f)); // 10000^{-dj/64}
  float f = (float)s * e;
  cosT[i] = cosf(f);
  sinT[i] = sinf(f);
}

// ------ rope apply (fp32 in, plain layout) -> bf16 out [B][H][S][DH] ------
__global__ __launch_bounds__(256) void k_rope_apply(const float* __restrict__ in,
                                                    const float* __restrict__ cosT,
                                                    const float* __restrict__ sinT,
                                                    unsigned short* __restrict__ out) {
  int p = blockIdx.x * 256 + threadIdx.x;  // < B*S*H*64
  int dj = p & 63;
  int h  = (p >> 6) & (NH - 1);
  int s  = (p >> 10) & (S_LEN - 1);
  int b  = p >> 21;
  const float2 xy = *(const float2*)(in + (size_t)(b * S_LEN + s) * DMODEL + h * DHD + 2 * dj);
  float c  = cosT[(s << 6) + dj];
  float sn = sinT[(s << 6) + dj];
  float re = xy.x * c - xy.y * sn;
  float ro = xy.x * sn + xy.y * c;
  unsigned int pack = (unsigned int)f2bf(re) | ((unsigned int)f2bf(ro) << 16);
  *(unsigned int*)(out + (size_t)((b * NH + h) * S_LEN + s) * DHD + 2 * dj) = pack;
}

// ---------------- GEMM: C[M][N] = A[M][K](bf16) * BT[N][K](bf16)^T ----------------
// MODE 0: C = float, plain row-major.  MODE 1: C = bf16, [B][H][S][DH] layout.
template <int MODE>
__global__ __launch_bounds__(256) void k_gemm(const unsigned short* __restrict__ A,
                                              const unsigned short* __restrict__ BT,
                                              void* __restrict__ Cv,
                                              int M, int N, int K) {
  __shared__ unsigned short Asm[128 * 32];
  __shared__ unsigned short Bsm[128 * 32];
  const int t = threadIdx.x;
  const int lane = t & 63;
  const int wave = t >> 6;
  const int hi = lane >> 4, lr = lane & 15;
  const int wr = wave >> 1, wc = wave & 1;
  const int bn = blockIdx.x, bm = blockIdx.y;

  const int c1 = t, c2 = t + 256;
  const int r1 = c1 >> 2, q1 = c1 & 3, g1 = q1 ^ (r1 & 3);
  const int r2 = c2 >> 2, q2 = c2 & 3, g2 = q2 ^ (r2 & 3);
  const unsigned short* a1 = A + (size_t)(bm * 128 + r1) * K + g1 * 8;
  const unsigned short* a2 = A + (size_t)(bm * 128 + r2) * K + g2 * 8;
  const unsigned short* b1 = BT + (size_t)(bn * 128 + r1) * K + g1 * 8;
  const unsigned short* b2 = BT + (size_t)(bn * 128 + r2) * K + g2 * 8;

  int aoff[4], boff[4];
#pragma unroll
  for (int m = 0; m < 4; ++m) {
    int row = wr * 64 + m * 16 + lr;
    aoff[m] = row * 64 + ((hi ^ (row & 3)) * 16);
  }
#pragma unroll
  for (int n = 0; n < 4; ++n) {
    int row = wc * 64 + n * 16 + lr;
    boff[n] = row * 64 + ((hi ^ (row & 3)) * 16);
  }

  f32x4 acc[4][4];
#pragma unroll
  for (int m = 0; m < 4; ++m)
#pragma unroll
    for (int n = 0; n < 4; ++n) {
      f32x4 z = {0.f, 0.f, 0.f, 0.f};
      acc[m][n] = z;
    }

  for (int k0 = 0; k0 < K; k0 += 32) {
    async_cp16((char*)Asm + c1 * 16, a1 + k0);
    async_cp16((char*)Asm + c2 * 16, a2 + k0);
    async_cp16((char*)Bsm + c1 * 16, b1 + k0);
    async_cp16((char*)Bsm + c2 * 16, b2 + k0);
    __syncthreads();
    bf16x8 af[4], bfv[4];
#pragma unroll
    for (int m = 0; m < 4; ++m) af[m] = *(const bf16x8*)((const char*)Asm + aoff[m]);
#pragma unroll
    for (int n = 0; n < 4; ++n) bfv[n] = *(const bf16x8*)((const char*)Bsm + boff[n]);
#pragma unroll
    for (int m = 0; m < 4; ++m)
#pragma unroll
      for (int n = 0; n < 4; ++n)
        acc[m][n] = __builtin_amdgcn_mfma_f32_16x16x32_bf16(af[m], bfv[n], acc[m][n], 0, 0, 0);
    __syncthreads();
  }

  if (MODE == 0) {
    float* C = (float*)Cv;
#pragma unroll
    for (int m = 0; m < 4; ++m) {
      int row0 = bm * 128 + wr * 64 + m * 16 + hi * 4;
#pragma unroll
      for (int n = 0; n < 4; ++n) {
        int col = bn * 128 + wc * 64 + n * 16 + lr;
#pragma unroll
        for (int j = 0; j < 4; ++j) C[(size_t)(row0 + j) * N + col] = acc[m][n][j];
      }
    }
  } else {
    unsigned short* C = (unsigned short*)Cv;
#pragma unroll
    for (int m = 0; m < 4; ++m) {
      int row0 = bm * 128 + wr * 64 + m * 16 + hi * 4;
#pragma unroll
      for (int n = 0; n < 4; ++n) {
        int col = bn * 128 + wc * 64 + n * 16 + lr;
        int h = col >> 7, dh = col & 127;
#pragma unroll
        for (int j = 0; j < 4; ++j) {
          int row = row0 + j;
          int b = row >> 11, s = row & 2047;
          C[((size_t)(b * NH + h) * S_LEN + s) * DHD + dh] = f2bf(acc[m][n][j]);
        }
      }
    }
  }
}

// ---------------- causal flash attention ----------------
// Q,K,V: [B][H][S][DH] bf16.  O: [B][S][H][DH] bf16.
__global__ __launch_bounds__(256) void k_flash_attn(const unsigned short* __restrict__ Qg,
                                                    const unsigned short* __restrict__ Kg,
                                                    const unsigned short* __restrict__ Vg,
                                                    unsigned short* __restrict__ Og) {
  __shared__ unsigned short K_lds[64 * 128];   // [kv][dh], XOR-swizzled rows
  __shared__ unsigned short VT_lds[128 * 64];  // [dh][kv], XOR-swizzled rows
  __shared__ unsigned short P_lds[4][16 * 72]; // per-wave, padded

  const int qt = blockIdx.x, h = blockIdx.y, b = blockIdx.z;
  const int t = threadIdx.x;
  const int lane = t & 63, wave = t >> 6;
  const int hi = lane >> 4, lr = lane & 15;

  const size_t head = (size_t)(b * NH + h) * S_LEN * DHD;
  const unsigned short* Q = Qg + head;
  const unsigned short* K = Kg + head;
  const unsigned short* V = Vg + head;

  const int q0 = qt * 64;
  const int qbase = q0 + wave * 16;

  bf16x8 qf[4];
  {
    const unsigned short* qrow = Q + (size_t)(qbase + lr) * DHD;
#pragma unroll
    for (int kc = 0; kc < 4; ++kc) qf[kc] = *(const bf16x8*)(qrow + kc * 32 + hi * 8);
  }

  f32x4 of[8];
#pragma unroll
  for (int i = 0; i < 8; ++i) {
    f32x4 z = {0.f, 0.f, 0.f, 0.f};
    of[i] = z;
  }
  float mrow[4] = {-INFINITY, -INFINITY, -INFINITY, -INFINITY};
  float lsum[4] = {0.f, 0.f, 0.f, 0.f};
  const float sc = 0.08838834764831845f;  // 1/sqrt(128)

  for (int tt = 0; tt <= qt; ++tt) {
    const int kv0 = tt * 64;
    __syncthreads();  // protect LDS from previous iteration's readers

    // stage K: pre-swizzled global source, linear LDS dest
#pragma unroll
    for (int i = 0; i < 4; ++i) {
      int c = t + 256 * i;
      int r = c >> 4, c16 = c & 15;
      int gc = c16 ^ (r & 7);
      async_cp16((char*)K_lds + c * 16, K + (size_t)(kv0 + r) * DHD + gc * 8);
    }
    // stage V transposed (reg-staged, swizzled writes)
#pragma unroll
    for (int i = 0; i < 2; ++i) {
      int u = t + 256 * i;
      int dc = u & 15, sp = u >> 4;  // dh-chunk, s-pair
      const unsigned short* vp = V + (size_t)(kv0 + 2 * sp) * DHD + dc * 8;
      ushort8 va = *(const ushort8*)vp;
      ushort8 vb = *(const ushort8*)(vp + DHD);
#pragma unroll
      for (int j = 0; j < 8; ++j) {
        int row = dc * 8 + j;
        unsigned int val = (unsigned int)va[j] | ((unsigned int)vb[j] << 16);
        int bc = (4 * sp) ^ ((row & 7) << 4);
        *(unsigned int*)((char*)VT_lds + row * 128 + bc) = val;
      }
    }
    __syncthreads();

    // QK^T: S[16 q][64 kv] per wave
    f32x4 sf[4];
#pragma unroll
    for (int n = 0; n < 4; ++n) {
      f32x4 z = {0.f, 0.f, 0.f, 0.f};
      sf[n] = z;
    }
#pragma unroll
    for (int n = 0; n < 4; ++n) {
      const int kr = n * 16 + lr;
#pragma unroll
      for (int kc = 0; kc < 4; ++kc) {
        bf16x8 kf = *(const bf16x8*)((const char*)K_lds + kr * 256 +
                                     ((kc * 64 + hi * 16) ^ ((kr & 7) << 4)));
        sf[n] = __builtin_amdgcn_mfma_f32_16x16x32_bf16(qf[kc], kf, sf[n], 0, 0, 0);
      }
    }

    // masked online softmax (row stats shuffle over 16-lane groups)
    float pv[4][4];
    float tmax[4] = {-INFINITY, -INFINITY, -INFINITY, -INFINITY};
#pragma unroll
    for (int n = 0; n < 4; ++n) {
      int kvcol = kv0 + n * 16 + lr;
#pragma unroll
      for (int j = 0; j < 4; ++j) {
        int qr = qbase + hi * 4 + j;
        float v = sf[n][j] * sc;
        if (kvcol > qr) v = -INFINITY;
        pv[n][j] = v;
        tmax[j] = fmaxf(tmax[j], v);
      }
    }
#pragma unroll
    for (int j = 0; j < 4; ++j) {
#pragma unroll
      for (int m = 1; m < 16; m <<= 1) tmax[j] = fmaxf(tmax[j], __shfl_xor(tmax[j], m));
    }
    float corr[4];
#pragma unroll
    for (int j = 0; j < 4; ++j) {
      float mn = fmaxf(mrow[j], tmax[j]);
      corr[j] = __expf(mrow[j] - mn);
      mrow[j] = mn;
      float rs = 0.f;
#pragma unroll
      for (int n = 0; n < 4; ++n) {
        float e = __expf(pv[n][j] - mn);
        pv[n][j] = e;
        rs += e;
      }
#pragma unroll
      for (int m = 1; m < 16; m <<= 1) rs += __shfl_xor(rs, m);
      lsum[j] = lsum[j] * corr[j] + rs;
    }
#pragma unroll
    for (int nd = 0; nd < 8; ++nd)
#pragma unroll
      for (int j = 0; j < 4; ++j) of[nd][j] *= corr[j];

    // P -> LDS (bf16), wave-private, no barrier needed
#pragma unroll
    for (int n = 0; n < 4; ++n)
#pragma unroll
      for (int j = 0; j < 4; ++j)
        P_lds[wave][(hi * 4 + j) * 72 + n * 16 + lr] = f2bf(pv[n][j]);

    // PV: O[16 q][128 dh] += P[16][64] * V[64][128]
#pragma unroll
    for (int kc = 0; kc < 2; ++kc) {
      bf16x8 pa = *(const bf16x8*)(&P_lds[wave][lr * 72 + kc * 32 + hi * 8]);
#pragma unroll
      for (int nd = 0; nd < 8; ++nd) {
        const int vr = nd * 16 + lr;
        bf16x8 vf = *(const bf16x8*)((const char*)VT_lds + vr * 128 +
                                     ((kc * 64 + hi * 16) ^ ((vr & 7) << 4)));
        of[nd] = __builtin_amdgcn_mfma_f32_16x16x32_bf16(pa, vf, of[nd], 0, 0, 0);
      }
    }
  }

  // epilogue: normalize, write [B][S][H][DH]
  float inv[4];
#pragma unroll
  for (int j = 0; j < 4; ++j) inv[j] = 1.0f / lsum[j];
#pragma unroll
  for (int nd = 0; nd < 8; ++nd)
#pragma unroll
    for (int j = 0; j < 4; ++j) {
      int qr = qbase + hi * 4 + j;
      Og[((size_t)(b * S_LEN + qr) * NH + h) * DHD + nd * 16 + lr] = f2bf(of[nd][j] * inv[j]);
    }
}

// ---------------- launch ----------------
extern "C" void kernel_launch(void* const* d_in, const int* in_sizes, int n_in,
                              void* d_out, int out_size, void* d_ws, size_t ws_size,
                              hipStream_t stream) {
  const float* x  = (const float*)d_in[0];
  const float* wq = (const float*)d_in[1];
  const float* wk = (const float*)d_in[2];
  const float* wv = (const float*)d_in[3];
  const float* wo = (const float*)d_in[4];
  float* out = (float*)d_out;

  char* ws = (char*)d_ws;
  unsigned short* xb    = (unsigned short*)(ws);              // 16 MB (reused as attn out)
  unsigned short* wqT   = (unsigned short*)(ws + 16777216);   // 8 MB each
  unsigned short* wkT   = (unsigned short*)(ws + 25165824);
  unsigned short* wvT   = (unsigned short*)(ws + 33554432);
  unsigned short* woT   = (unsigned short*)(ws + 41943040);
  float*          qf    = (float*)(ws + 50331648);            // 32 MB fp32 scratch (q then k)
  unsigned short* qb    = (unsigned short*)(ws + 83886080);   // 16 MB
  unsigned short* kb    = (unsigned short*)(ws + 100663296);  // 16 MB
  unsigned short* vb    = (unsigned short*)(ws + 117440512);  // 16 MB
  float*          cosT  = (float*)(ws + 134217728);           // 512 KB
  float*          sinT  = (float*)(ws + 134742016);           // 512 KB
  unsigned short* attnb = xb;

  k_cast_bf16<<<8192, 256, 0, stream>>>(x, xb, 2097152);
  dim3 tg(32, 32);
  k_transpose_cast<<<tg, 256, 0, stream>>>(wq, wqT);
  k_transpose_cast<<<tg, 256, 0, stream>>>(wk, wkT);
  k_transpose_cast<<<tg, 256, 0, stream>>>(wv, wvT);
  k_transpose_cast<<<tg, 256, 0, stream>>>(wo, woT);
  k_rope_table<<<512, 256, 0, stream>>>(cosT, sinT);

  dim3 gg(16, 32);  // N/128, M/128
  k_gemm<0><<<gg, 256, 0, stream>>>(xb, wqT, qf, 4096, 2048, 2048);
  k_rope_apply<<<16384, 256, 0, stream>>>(qf, cosT, sinT, qb);
  k_gemm<0><<<gg, 256, 0, stream>>>(xb, wkT, qf, 4096, 2048, 2048);
  k_rope_apply<<<16384, 256, 0, stream>>>(qf, cosT, sinT, kb);
  k_gemm<1><<<gg, 256, 0, stream>>>(xb, wvT, vb, 4096, 2048, 2048);

  dim3 ga(32, 16, 2);  // q-tiles, heads, batch
  k_flash_attn<<<ga, 256, 0, stream>>>(qb, kb, vb, attnb);

  k_gemm<0><<<gg, 256, 0, stream>>>(attnb, woT, out, 4096, 2048, 2048);
}

// Round 2
// 402.713 us; speedup vs baseline: 1.3486x; 1.3486x over previous
//
#include <hip/hip_runtime.h>
#include <hip/hip_bf16.h>
#include <stdint.h>

#define B_SZ   2
#define S_LEN  2048
#define DMODEL 2048
#define NH     16
#define DHD    128

typedef __attribute__((ext_vector_type(8))) __bf16 bf16x8;
typedef __attribute__((ext_vector_type(4))) float  f32x4;
typedef __attribute__((ext_vector_type(4))) float  float4v;
typedef __attribute__((ext_vector_type(8))) unsigned short ushort8;
typedef __attribute__((ext_vector_type(4))) unsigned short ushort4v;

__device__ __forceinline__ unsigned short f2bf(float f) {
  unsigned int u = __float_as_uint(f);
  unsigned int r = (u + 0x7fffu + ((u >> 16) & 1u)) >> 16;
  return (unsigned short)r;
}

__device__ __forceinline__ void async_cp16(void* lds, const void* g) {
  __builtin_amdgcn_global_load_lds(
      (const __attribute__((address_space(1))) void*)g,
      (__attribute__((address_space(3))) void*)lds, 16, 0, 0);
}

// ---------------- elementwise cast x -> bf16 ----------------
__global__ __launch_bounds__(256) void k_cast_bf16(const float* __restrict__ in,
                                                   unsigned short* __restrict__ out,
                                                   int n4) {
  int i = blockIdx.x * 256 + threadIdx.x;
  if (i >= n4) return;
  float4v v = ((const float4v*)in)[i];
  ushort4v o;
  o[0] = f2bf(v[0]); o[1] = f2bf(v[1]); o[2] = f2bf(v[2]); o[3] = f2bf(v[3]);
  ((ushort4v*)out)[i] = o;
}

// ---------------- transpose + cast W[K][N] -> WT[N][K] bf16 ----------------
__global__ __launch_bounds__(256) void k_transpose_cast(const float* __restrict__ W,
                                                        unsigned short* __restrict__ WT) {
  __shared__ unsigned short tile[64 * 72];
  const int n0 = blockIdx.x * 64;
  const int k0 = blockIdx.y * 64;
  const int t = threadIdx.x;
#pragma unroll
  for (int i = 0; i < 4; ++i) {
    int c = t + 256 * i;
    int r = c >> 4, c4 = c & 15;
    float4v v = *(const float4v*)(W + (size_t)(k0 + r) * DMODEL + n0 + c4 * 4);
    ushort4v o;
    o[0] = f2bf(v[0]); o[1] = f2bf(v[1]); o[2] = f2bf(v[2]); o[3] = f2bf(v[3]);
    *(ushort4v*)(&tile[r * 72 + c4 * 4]) = o;
  }
  __syncthreads();
#pragma unroll
  for (int i = 0; i < 2; ++i) {
    int c = t + 256 * i;
    int n = c >> 3, k8 = c & 7;
    ushort8 o;
#pragma unroll
    for (int j = 0; j < 8; ++j) o[j] = tile[(k8 * 8 + j) * 72 + n];
    *(ushort8*)(WT + (size_t)(n0 + n) * DMODEL + k0 + k8 * 8) = o;
  }
}

// ---------------- rope cos/sin table [S][64] ----------------
__global__ __launch_bounds__(256) void k_rope_table(float* __restrict__ cosT,
                                                    float* __restrict__ sinT) {
  int i = blockIdx.x * 256 + threadIdx.x;  // < S_LEN*64
  int s = i >> 6, dj = i & 63;
  float e = __expf(-9.210340371976184f * (float)dj * (1.0f / 64.0f)); // 10000^{-dj/64}
  float f = (float)s * e;
  cosT[i] = cosf(f);
  sinT[i] = sinf(f);
}

// ---------------- GEMM: C[M][N] = A[M][K](bf16) * BT[N][K](bf16)^T ----------------
// MODE 0: C = float, plain row-major.
// MODE 1: C = bf16, [B][H][S][DH] layout.
// MODE 2: C = bf16, [B][H][S][DH] layout with fused interleaved RoPE.
template <int MODE>
__global__ __launch_bounds__(256) void k_gemm(const unsigned short* __restrict__ A,
                                              const unsigned short* __restrict__ BT,
                                              void* __restrict__ Cv,
                                              const float* __restrict__ cosT,
                                              const float* __restrict__ sinT,
                                              int M, int N, int K) {
  __shared__ unsigned short Asm[128 * 32];
  __shared__ unsigned short Bsm[128 * 32];
  const int t = threadIdx.x;
  const int lane = t & 63;
  const int wave = t >> 6;
  const int hi = lane >> 4, lr = lane & 15;
  const int wr = wave >> 1, wc = wave & 1;
  const int bn = blockIdx.x, bm = blockIdx.y;

  const int c1 = t, c2 = t + 256;
  const int r1 = c1 >> 2, q1 = c1 & 3, g1 = q1 ^ (r1 & 3);
  const int r2 = c2 >> 2, q2 = c2 & 3, g2 = q2 ^ (r2 & 3);
  const unsigned short* a1 = A + (size_t)(bm * 128 + r1) * K + g1 * 8;
  const unsigned short* a2 = A + (size_t)(bm * 128 + r2) * K + g2 * 8;
  const unsigned short* b1 = BT + (size_t)(bn * 128 + r1) * K + g1 * 8;
  const unsigned short* b2 = BT + (size_t)(bn * 128 + r2) * K + g2 * 8;

  int aoff[4], boff[4];
#pragma unroll
  for (int m = 0; m < 4; ++m) {
    int row = wr * 64 + m * 16 + lr;
    aoff[m] = row * 64 + ((hi ^ (row & 3)) * 16);
  }
#pragma unroll
  for (int n = 0; n < 4; ++n) {
    int row = wc * 64 + n * 16 + lr;
    boff[n] = row * 64 + ((hi ^ (row & 3)) * 16);
  }

  f32x4 acc[4][4];
#pragma unroll
  for (int m = 0; m < 4; ++m)
#pragma unroll
    for (int n = 0; n < 4; ++n) {
      f32x4 z = {0.f, 0.f, 0.f, 0.f};
      acc[m][n] = z;
    }

  for (int k0 = 0; k0 < K; k0 += 32) {
    async_cp16((char*)Asm + c1 * 16, a1 + k0);
    async_cp16((char*)Asm + c2 * 16, a2 + k0);
    async_cp16((char*)Bsm + c1 * 16, b1 + k0);
    async_cp16((char*)Bsm + c2 * 16, b2 + k0);
    __syncthreads();
    bf16x8 af[4], bfv[4];
#pragma unroll
    for (int m = 0; m < 4; ++m) af[m] = *(const bf16x8*)((const char*)Asm + aoff[m]);
#pragma unroll
    for (int n = 0; n < 4; ++n) bfv[n] = *(const bf16x8*)((const char*)Bsm + boff[n]);
#pragma unroll
    for (int m = 0; m < 4; ++m)
#pragma unroll
      for (int n = 0; n < 4; ++n)
        acc[m][n] = __builtin_amdgcn_mfma_f32_16x16x32_bf16(af[m], bfv[n], acc[m][n], 0, 0, 0);
    __syncthreads();
  }

  if (MODE == 0) {
    float* C = (float*)Cv;
#pragma unroll
    for (int m = 0; m < 4; ++m) {
      int row0 = bm * 128 + wr * 64 + m * 16 + hi * 4;
#pragma unroll
      for (int n = 0; n < 4; ++n) {
        int col = bn * 128 + wc * 64 + n * 16 + lr;
#pragma unroll
        for (int j = 0; j < 4; ++j) C[(size_t)(row0 + j) * N + col] = acc[m][n][j];
      }
    }
  } else if (MODE == 1) {
    unsigned short* C = (unsigned short*)Cv;
#pragma unroll
    for (int m = 0; m < 4; ++m) {
      int row0 = bm * 128 + wr * 64 + m * 16 + hi * 4;
#pragma unroll
      for (int n = 0; n < 4; ++n) {
        int col = bn * 128 + wc * 64 + n * 16 + lr;
        int h = col >> 7, dh = col & 127;
#pragma unroll
        for (int j = 0; j < 4; ++j) {
          int row = row0 + j;
          int b = row >> 11, s = row & 2047;
          C[((size_t)(b * NH + h) * S_LEN + s) * DHD + dh] = f2bf(acc[m][n][j]);
        }
      }
    }
  } else {
    // fused RoPE epilogue: adjacent (even,odd) dims live in adjacent lanes
    unsigned short* C = (unsigned short*)Cv;
#pragma unroll
    for (int m = 0; m < 4; ++m) {
      int row0 = bm * 128 + wr * 64 + m * 16 + hi * 4;
#pragma unroll
      for (int n = 0; n < 4; ++n) {
        int d = wc * 64 + n * 16 + lr;  // 0..127 within head
        int hh = bn;                    // head index (N=2048, 128-wide blocks)
        int dj = d >> 1;
        float sgn = (d & 1) ? 1.f : -1.f;
#pragma unroll
        for (int j = 0; j < 4; ++j) {
          int row = row0 + j;
          int b = row >> 11, s = row & 2047;
          float v = acc[m][n][j];
          float p = __shfl_xor(v, 1);
          float cc = cosT[(s << 6) + dj];
          float sn = sinT[(s << 6) + dj];
          float r = v * cc + sgn * p * sn;
          C[((size_t)(b * NH + hh) * S_LEN + s) * DHD + d] = f2bf(r);
        }
      }
    }
  }
}

// ---------------- causal flash attention ----------------
// Q,K,V: [B][H][S][DH] bf16.  O: [B][S][H][DH] bf16.
// Triangle-paired q-tiles (uniform work), double-buffered K/V pipeline.
__global__ __launch_bounds__(256) void k_flash_attn(const unsigned short* __restrict__ Qg,
                                                    const unsigned short* __restrict__ Kg,
                                                    const unsigned short* __restrict__ Vg,
                                                    unsigned short* __restrict__ Og) {
  __shared__ unsigned short K_lds[2][64 * 128];   // [kv][dh], swizzled slots
  __shared__ unsigned short VT_lds[2][128 * 64];  // [dh][kv], swizzled slots
  __shared__ unsigned short P_lds[4][16 * 72];    // per-wave, swizzled

  const int pq = blockIdx.x, h = blockIdx.y, b = blockIdx.z;
  const int t = threadIdx.x;
  const int lane = t & 63, wave = t >> 6;
  const int hi = lane >> 4, lr = lane & 15;

  const size_t head = (size_t)(b * NH + h) * (size_t)(S_LEN * DHD);
  const unsigned short* Q = Qg + head;
  const unsigned short* Kp = Kg + head;
  const unsigned short* Vp = Vg + head;

  // K staging: chunk c = t + 256*i -> LDS row r = (t>>4)+16i, slot t&15,
  // global col chunk = slot ^ (r&7)  (constant across i since 16i%8==0)
  const int kr0 = t >> 4;
  const int kgc = (t & 15) ^ (kr0 & 7);
  const unsigned short* Kbase = Kp + (size_t)kr0 * DHD + kgc * 8;
  const int kdst = t * 16;

  // V staging: u = t + 256*i2 -> dc = t&15 (dh chunk), sp = (t>>4)+16*i2 (kv pair)
  const int vdc = t & 15, vsp0 = t >> 4;
  const unsigned short* Vbase = Vp + (size_t)(2 * vsp0) * DHD + vdc * 8;

  const float sc = 0.08838834764831845f;  // 1/sqrt(128)

  for (int pass = 0; pass < 2; ++pass) {
    const int qt = (pass == 0) ? pq : (31 - pq);
    const int nt = qt + 1;
    const int qbase = qt * 64 + wave * 16;

    bf16x8 qf[4];
    {
      const unsigned short* qrow = Q + (size_t)(qbase + lr) * DHD;
#pragma unroll
      for (int kc = 0; kc < 4; ++kc) qf[kc] = *(const bf16x8*)(qrow + kc * 32 + hi * 8);
    }

    f32x4 of[8];
#pragma unroll
    for (int i = 0; i < 8; ++i) {
      f32x4 z = {0.f, 0.f, 0.f, 0.f};
      of[i] = z;
    }
    float mS[4] = {-INFINITY, -INFINITY, -INFINITY, -INFINITY};
    float lsum[4] = {0.f, 0.f, 0.f, 0.f};

    // prologue: stage tile 0 into buffer 0
    {
#pragma unroll
      for (int i = 0; i < 4; ++i)
        async_cp16((char*)K_lds[0] + kdst + i * 4096, Kbase + (size_t)(16 * i) * DHD);
      ushort8 va0 = *(const ushort8*)(Vbase);
      ushort8 vb0 = *(const ushort8*)(Vbase + DHD);
      ushort8 va1 = *(const ushort8*)(Vbase + (size_t)32 * DHD);
      ushort8 vb1 = *(const ushort8*)(Vbase + (size_t)33 * DHD);
#pragma unroll
      for (int j = 0; j < 8; ++j) {
        int row = vdc * 8 + j;
        int swz = ((j ^ vdc) & 7) << 4;
        *(unsigned int*)((char*)VT_lds[0] + row * 128 + ((4 * vsp0) ^ swz)) =
            (unsigned int)va0[j] | ((unsigned int)vb0[j] << 16);
        *(unsigned int*)((char*)VT_lds[0] + row * 128 + ((4 * (vsp0 + 16)) ^ swz)) =
            (unsigned int)va1[j] | ((unsigned int)vb1[j] << 16);
      }
    }
    __syncthreads();

    for (int tt = 0; tt < nt; ++tt) {
      const int cur = tt & 1;
      const int kv0 = tt * 64;
      const bool more = (tt + 1 < nt);
      const bool diag = (tt == qt);

      // issue next tile's loads (K async->LDS, V->regs)
      ushort8 va0, vb0, va1, vb1;
      if (more) {
        const unsigned short* ks = Kbase + (size_t)(kv0 + 64) * DHD;
#pragma unroll
        for (int i = 0; i < 4; ++i)
          async_cp16((char*)K_lds[cur ^ 1] + kdst + i * 4096, ks + (size_t)(16 * i) * DHD);
        const unsigned short* vs = Vbase + (size_t)(kv0 + 64) * DHD;
        va0 = *(const ushort8*)(vs);
        vb0 = *(const ushort8*)(vs + DHD);
        va1 = *(const ushort8*)(vs + (size_t)32 * DHD);
        vb1 = *(const ushort8*)(vs + (size_t)33 * DHD);
      }

      // QK^T: S[16 q][64 kv] per wave
      const char* Kb = (const char*)K_lds[cur];
      f32x4 sf[4];
#pragma unroll
      for (int n = 0; n < 4; ++n) {
        f32x4 z = {0.f, 0.f, 0.f, 0.f};
        sf[n] = z;
      }
      __builtin_amdgcn_s_setprio(1);
#pragma unroll
      for (int n = 0; n < 4; ++n) {
        const int kr = n * 16 + lr;
        const int kswz = (kr & 7) << 4;
#pragma unroll
        for (int kc = 0; kc < 4; ++kc) {
          bf16x8 kf = *(const bf16x8*)(Kb + kr * 256 + ((kc * 64 + hi * 16) ^ kswz));
          sf[n] = __builtin_amdgcn_mfma_f32_16x16x32_bf16(qf[kc], kf, sf[n], 0, 0, 0);
        }
      }
      __builtin_amdgcn_s_setprio(0);

      // masked online softmax (raw scores; scale folded into exp via fma)
      float pv[4][4];
      float tmax[4] = {-INFINITY, -INFINITY, -INFINITY, -INFINITY};
      if (diag) {
#pragma unroll
        for (int n = 0; n < 4; ++n) {
          int kvcol = kv0 + n * 16 + lr;
#pragma unroll
          for (int j = 0; j < 4; ++j) {
            float v = (kvcol > qbase + hi * 4 + j) ? -INFINITY : sf[n][j];
            pv[n][j] = v;
            tmax[j] = fmaxf(tmax[j], v);
          }
        }
      } else {
#pragma unroll
        for (int n = 0; n < 4; ++n)
#pragma unroll
          for (int j = 0; j < 4; ++j) {
            float v = sf[n][j];
            pv[n][j] = v;
            tmax[j] = fmaxf(tmax[j], v);
          }
      }
#pragma unroll
      for (int j = 0; j < 4; ++j) {
#pragma unroll
        for (int m = 1; m < 16; m <<= 1) tmax[j] = fmaxf(tmax[j], __shfl_xor(tmax[j], m));
      }
      float corr[4];
#pragma unroll
      for (int j = 0; j < 4; ++j) {
        float mn = fmaxf(mS[j], tmax[j]);
        corr[j] = __expf((mS[j] - mn) * sc);
        mS[j] = mn;
        float mns = mn * sc;
        float rs = 0.f;
#pragma unroll
        for (int n = 0; n < 4; ++n) {
          float e = __expf(__builtin_fmaf(pv[n][j], sc, -mns));
          pv[n][j] = e;
          rs += e;
        }
#pragma unroll
        for (int m = 1; m < 16; m <<= 1) rs += __shfl_xor(rs, m);
        lsum[j] = lsum[j] * corr[j] + rs;
      }
#pragma unroll
      for (int nd = 0; nd < 8; ++nd)
#pragma unroll
        for (int j = 0; j < 4; ++j) of[nd][j] *= corr[j];

      // P -> LDS bf16, swizzled: col' = col ^ ((row>>2)<<3)
#pragma unroll
      for (int n = 0; n < 4; ++n)
#pragma unroll
        for (int j = 0; j < 4; ++j) {
          int row = hi * 4 + j;
          int col = (n * 16 + lr) ^ (hi << 3);
          P_lds[wave][row * 72 + col] = f2bf(pv[n][j]);
        }

      // PV: O[16 q][128 dh] += P[16][64] * V[64][128]
      const char* Vb = (const char*)VT_lds[cur];
      __builtin_amdgcn_s_setprio(1);
#pragma unroll
      for (int kc = 0; kc < 2; ++kc) {
        bf16x8 pa = *(const bf16x8*)((const char*)P_lds[wave] + lr * 144 +
                                     ((kc * 64 + hi * 16) ^ (((lr >> 2) & 3) << 4)));
#pragma unroll
        for (int nd = 0; nd < 8; ++nd) {
          const int vr = nd * 16 + lr;
          const int vswz = ((vr & 7) ^ ((vr >> 3) & 7)) << 4;
          bf16x8 vf = *(const bf16x8*)(Vb + vr * 128 + ((kc * 64 + hi * 16) ^ vswz));
          of[nd] = __builtin_amdgcn_mfma_f32_16x16x32_bf16(pa, vf, of[nd], 0, 0, 0);
        }
      }
      __builtin_amdgcn_s_setprio(0);

      // complete next tile's V staging (reg -> LDS, swizzled)
      if (more) {
        char* Vw = (char*)VT_lds[cur ^ 1];
#pragma unroll
        for (int j = 0; j < 8; ++j) {
          int row = vdc * 8 + j;
          int swz = ((j ^ vdc) & 7) << 4;
          *(unsigned int*)(Vw + row * 128 + ((4 * vsp0) ^ swz)) =
              (unsigned int)va0[j] | ((unsigned int)vb0[j] << 16);
          *(unsigned int*)(Vw + row * 128 + ((4 * (vsp0 + 16)) ^ swz)) =
              (unsigned int)va1[j] | ((unsigned int)vb1[j] << 16);
        }
      }
      __syncthreads();
    }

    // epilogue: normalize, write [B][S][H][DH]
    float inv[4];
#pragma unroll
    for (int j = 0; j < 4; ++j) inv[j] = 1.0f / lsum[j];
#pragma unroll
    for (int nd = 0; nd < 8; ++nd)
#pragma unroll
      for (int j = 0; j < 4; ++j) {
        int qr = qbase + hi * 4 + j;
        Og[((size_t)(b * S_LEN + qr) * NH + h) * DHD + nd * 16 + lr] = f2bf(of[nd][j] * inv[j]);
      }
  }
}

// ---------------- launch ----------------
extern "C" void kernel_launch(void* const* d_in, const int* in_sizes, int n_in,
                              void* d_out, int out_size, void* d_ws, size_t ws_size,
                              hipStream_t stream) {
  const float* x  = (const float*)d_in[0];
  const float* wq = (const float*)d_in[1];
  const float* wk = (const float*)d_in[2];
  const float* wv = (const float*)d_in[3];
  const float* wo = (const float*)d_in[4];
  float* out = (float*)d_out;

  char* ws = (char*)d_ws;
  unsigned short* xb    = (unsigned short*)(ws);              // 16 MB (reused as attn out)
  unsigned short* wqT   = (unsigned short*)(ws + 16777216);   // 8 MB each
  unsigned short* wkT   = (unsigned short*)(ws + 25165824);
  unsigned short* wvT   = (unsigned short*)(ws + 33554432);
  unsigned short* woT   = (unsigned short*)(ws + 41943040);
  unsigned short* qb    = (unsigned short*)(ws + 50331648);   // 16 MB each
  unsigned short* kb    = (unsigned short*)(ws + 67108864);
  unsigned short* vb    = (unsigned short*)(ws + 83886080);
  float*          cosT  = (float*)(ws + 100663296);           // 512 KB
  float*          sinT  = (float*)(ws + 101187584);
  unsigned short* attnb = xb;

  k_cast_bf16<<<8192, 256, 0, stream>>>(x, xb, 2097152);
  dim3 tg(32, 32);
  k_transpose_cast<<<tg, 256, 0, stream>>>(wq, wqT);
  k_transpose_cast<<<tg, 256, 0, stream>>>(wk, wkT);
  k_transpose_cast<<<tg, 256, 0, stream>>>(wv, wvT);
  k_transpose_cast<<<tg, 256, 0, stream>>>(wo, woT);
  k_rope_table<<<512, 256, 0, stream>>>(cosT, sinT);

  dim3 gg(16, 32);  // N/128, M/128
  k_gemm<2><<<gg, 256, 0, stream>>>(xb, wqT, qb, cosT, sinT, 4096, 2048, 2048);
  k_gemm<2><<<gg, 256, 0, stream>>>(xb, wkT, kb, cosT, sinT, 4096, 2048, 2048);
  k_gemm<1><<<gg, 256, 0, stream>>>(xb, wvT, vb, nullptr, nullptr, 4096, 2048, 2048);

  dim3 ga(16, 16, 2);  // q-tile pairs, heads, batch
  k_flash_attn<<<ga, 256, 0, stream>>>(qb, kb, vb, attnb);

  k_gemm<0><<<gg, 256, 0, stream>>>(attnb, woT, out, nullptr, nullptr, 4096, 2048, 2048);
}

// Round 3
// 309.858 us; speedup vs baseline: 1.7527x; 1.2997x over previous
//
#include <hip/hip_runtime.h>
#include <hip/hip_bf16.h>
#include <stdint.h>

#define B_SZ   2
#define S_LEN  2048
#define DMODEL 2048
#define NH     16
#define DHD    128

typedef __attribute__((ext_vector_type(8))) __bf16 bf16x8;
typedef __attribute__((ext_vector_type(4))) float  f32x4;
typedef __attribute__((ext_vector_type(4))) float  float4v;
typedef __attribute__((ext_vector_type(8))) unsigned short ushort8;
typedef __attribute__((ext_vector_type(4))) unsigned short ushort4v;

__device__ __forceinline__ unsigned short f2bf(float f) {
  unsigned int u = __float_as_uint(f);
  unsigned int r = (u + 0x7fffu + ((u >> 16) & 1u)) >> 16;
  return (unsigned short)r;
}

__device__ __forceinline__ unsigned int cvt_pk_bf16(float lo, float hi) {
  unsigned int r;
  asm("v_cvt_pk_bf16_f32 %0, %1, %2" : "=v"(r) : "v"(lo), "v"(hi));
  return r;
}

__device__ __forceinline__ void async_cp16(void* lds, const void* g) {
  __builtin_amdgcn_global_load_lds(
      (const __attribute__((address_space(1))) void*)g,
      (__attribute__((address_space(3))) void*)lds, 16, 0, 0);
}

// ---------------- elementwise cast x -> bf16 ----------------
__global__ __launch_bounds__(256) void k_cast_bf16(const float* __restrict__ in,
                                                   unsigned short* __restrict__ out,
                                                   int n4) {
  int i = blockIdx.x * 256 + threadIdx.x;
  if (i >= n4) return;
  float4v v = ((const float4v*)in)[i];
  ushort4v o;
  o[0] = f2bf(v[0]); o[1] = f2bf(v[1]); o[2] = f2bf(v[2]); o[3] = f2bf(v[3]);
  ((ushort4v*)out)[i] = o;
}

// ---------------- transpose + cast W[K][N] -> WT[N][K] bf16 ----------------
__global__ __launch_bounds__(256) void k_transpose_cast(const float* __restrict__ W,
                                                        unsigned short* __restrict__ WT) {
  __shared__ unsigned short tile[64 * 72];
  const int n0 = blockIdx.x * 64;
  const int k0 = blockIdx.y * 64;
  const int t = threadIdx.x;
#pragma unroll
  for (int i = 0; i < 4; ++i) {
    int c = t + 256 * i;
    int r = c >> 4, c4 = c & 15;
    float4v v = *(const float4v*)(W + (size_t)(k0 + r) * DMODEL + n0 + c4 * 4);
    ushort4v o;
    o[0] = f2bf(v[0]); o[1] = f2bf(v[1]); o[2] = f2bf(v[2]); o[3] = f2bf(v[3]);
    *(ushort4v*)(&tile[r * 72 + c4 * 4]) = o;
  }
  __syncthreads();
#pragma unroll
  for (int i = 0; i < 2; ++i) {
    int c = t + 256 * i;
    int n = c >> 3, k8 = c & 7;
    ushort8 o;
#pragma unroll
    for (int j = 0; j < 8; ++j) o[j] = tile[(k8 * 8 + j) * 72 + n];
    *(ushort8*)(WT + (size_t)(n0 + n) * DMODEL + k0 + k8 * 8) = o;
  }
}

// ---------------- rope cos/sin table [S][64] ----------------
__global__ __launch_bounds__(256) void k_rope_table(float* __restrict__ cosT,
                                                    float* __restrict__ sinT) {
  int i = blockIdx.x * 256 + threadIdx.x;  // < S_LEN*64
  int s = i >> 6, dj = i & 63;
  float e = __expf(-9.210340371976184f * (float)dj * (1.0f / 64.0f)); // 10000^{-dj/64}
  float f = (float)s * e;
  cosT[i] = cosf(f);
  sinT[i] = sinf(f);
}

// ---------------- shared GEMM core macro-ish helpers ----------------
// Both GEMM kernels: C[M][N] = A[M][K](bf16) * BT[N][K](bf16)^T, 128x128 tile.

// Plain fp32-output GEMM (used for the wo projection).
__global__ __launch_bounds__(256) void k_gemm0(const unsigned short* __restrict__ A,
                                               const unsigned short* __restrict__ BT,
                                               float* __restrict__ C,
                                               int M, int N, int K) {
  __shared__ unsigned short Asm[128 * 32];
  __shared__ unsigned short Bsm[128 * 32];
  const int t = threadIdx.x;
  const int lane = t & 63;
  const int wave = t >> 6;
  const int hi = lane >> 4, lr = lane & 15;
  const int wr = wave >> 1, wc = wave & 1;
  const int bn = blockIdx.x, bm = blockIdx.y;

  const int c1 = t, c2 = t + 256;
  const int r1 = c1 >> 2, q1 = c1 & 3, g1 = q1 ^ (r1 & 3);
  const int r2 = c2 >> 2, q2 = c2 & 3, g2 = q2 ^ (r2 & 3);
  const unsigned short* a1 = A + (size_t)(bm * 128 + r1) * K + g1 * 8;
  const unsigned short* a2 = A + (size_t)(bm * 128 + r2) * K + g2 * 8;
  const unsigned short* b1 = BT + (size_t)(bn * 128 + r1) * K + g1 * 8;
  const unsigned short* b2 = BT + (size_t)(bn * 128 + r2) * K + g2 * 8;

  int aoff[4], boff[4];
#pragma unroll
  for (int m = 0; m < 4; ++m) {
    int row = wr * 64 + m * 16 + lr;
    aoff[m] = row * 64 + ((hi ^ (row & 3)) * 16);
  }
#pragma unroll
  for (int n = 0; n < 4; ++n) {
    int row = wc * 64 + n * 16 + lr;
    boff[n] = row * 64 + ((hi ^ (row & 3)) * 16);
  }

  f32x4 acc[4][4];
#pragma unroll
  for (int m = 0; m < 4; ++m)
#pragma unroll
    for (int n = 0; n < 4; ++n) {
      f32x4 z = {0.f, 0.f, 0.f, 0.f};
      acc[m][n] = z;
    }

  for (int k0 = 0; k0 < K; k0 += 32) {
    async_cp16((char*)Asm + c1 * 16, a1 + k0);
    async_cp16((char*)Asm + c2 * 16, a2 + k0);
    async_cp16((char*)Bsm + c1 * 16, b1 + k0);
    async_cp16((char*)Bsm + c2 * 16, b2 + k0);
    __syncthreads();
    bf16x8 af[4], bfv[4];
#pragma unroll
    for (int m = 0; m < 4; ++m) af[m] = *(const bf16x8*)((const char*)Asm + aoff[m]);
#pragma unroll
    for (int n = 0; n < 4; ++n) bfv[n] = *(const bf16x8*)((const char*)Bsm + boff[n]);
#pragma unroll
    for (int m = 0; m < 4; ++m)
#pragma unroll
      for (int n = 0; n < 4; ++n)
        acc[m][n] = __builtin_amdgcn_mfma_f32_16x16x32_bf16(af[m], bfv[n], acc[m][n], 0, 0, 0);
    __syncthreads();
  }

#pragma unroll
  for (int m = 0; m < 4; ++m) {
    int row0 = bm * 128 + wr * 64 + m * 16 + hi * 4;
#pragma unroll
    for (int n = 0; n < 4; ++n) {
      int col = bn * 128 + wc * 64 + n * 16 + lr;
#pragma unroll
      for (int j = 0; j < 4; ++j) C[(size_t)(row0 + j) * N + col] = acc[m][n][j];
    }
  }
}

// Fused QKV projection: BT = [wqT;wkT;wvT] contiguous [6144][2048].
// bn<16 -> q (RoPE), bn<32 -> k (RoPE), else v (plain). Output [B][H][S][DH] bf16.
__global__ __launch_bounds__(256) void k_gemm_qkv(const unsigned short* __restrict__ A,
                                                  const unsigned short* __restrict__ BT,
                                                  unsigned short* __restrict__ qb,
                                                  unsigned short* __restrict__ kb,
                                                  unsigned short* __restrict__ vb,
                                                  const float* __restrict__ cosT,
                                                  const float* __restrict__ sinT) {
  const int K = DMODEL;
  __shared__ unsigned short Asm[128 * 32];
  __shared__ unsigned short Bsm[128 * 32];
  const int t = threadIdx.x;
  const int lane = t & 63;
  const int wave = t >> 6;
  const int hi = lane >> 4, lr = lane & 15;
  const int wr = wave >> 1, wc = wave & 1;
  const int bn = blockIdx.x, bm = blockIdx.y;

  const int c1 = t, c2 = t + 256;
  const int r1 = c1 >> 2, q1 = c1 & 3, g1 = q1 ^ (r1 & 3);
  const int r2 = c2 >> 2, q2 = c2 & 3, g2 = q2 ^ (r2 & 3);
  const unsigned short* a1 = A + (size_t)(bm * 128 + r1) * K + g1 * 8;
  const unsigned short* a2 = A + (size_t)(bm * 128 + r2) * K + g2 * 8;
  const unsigned short* b1 = BT + (size_t)(bn * 128 + r1) * K + g1 * 8;
  const unsigned short* b2 = BT + (size_t)(bn * 128 + r2) * K + g2 * 8;

  int aoff[4], boff[4];
#pragma unroll
  for (int m = 0; m < 4; ++m) {
    int row = wr * 64 + m * 16 + lr;
    aoff[m] = row * 64 + ((hi ^ (row & 3)) * 16);
  }
#pragma unroll
  for (int n = 0; n < 4; ++n) {
    int row = wc * 64 + n * 16 + lr;
    boff[n] = row * 64 + ((hi ^ (row & 3)) * 16);
  }

  f32x4 acc[4][4];
#pragma unroll
  for (int m = 0; m < 4; ++m)
#pragma unroll
    for (int n = 0; n < 4; ++n) {
      f32x4 z = {0.f, 0.f, 0.f, 0.f};
      acc[m][n] = z;
    }

  for (int k0 = 0; k0 < K; k0 += 32) {
    async_cp16((char*)Asm + c1 * 16, a1 + k0);
    async_cp16((char*)Asm + c2 * 16, a2 + k0);
    async_cp16((char*)Bsm + c1 * 16, b1 + k0);
    async_cp16((char*)Bsm + c2 * 16, b2 + k0);
    __syncthreads();
    bf16x8 af[4], bfv[4];
#pragma unroll
    for (int m = 0; m < 4; ++m) af[m] = *(const bf16x8*)((const char*)Asm + aoff[m]);
#pragma unroll
    for (int n = 0; n < 4; ++n) bfv[n] = *(const bf16x8*)((const char*)Bsm + boff[n]);
#pragma unroll
    for (int m = 0; m < 4; ++m)
#pragma unroll
      for (int n = 0; n < 4; ++n)
        acc[m][n] = __builtin_amdgcn_mfma_f32_16x16x32_bf16(af[m], bfv[n], acc[m][n], 0, 0, 0);
    __syncthreads();
  }

  const int sel = bn >> 4;
  const int hh = bn & 15;
  if (sel == 2) {
    // v projection: plain bf16, [B][H][S][DH]
#pragma unroll
    for (int m = 0; m < 4; ++m) {
      int row0 = bm * 128 + wr * 64 + m * 16 + hi * 4;
#pragma unroll
      for (int n = 0; n < 4; ++n) {
        int dh = wc * 64 + n * 16 + lr;
#pragma unroll
        for (int j = 0; j < 4; ++j) {
          int row = row0 + j;
          int b = row >> 11, s = row & 2047;
          vb[((size_t)(b * NH + hh) * S_LEN + s) * DHD + dh] = f2bf(acc[m][n][j]);
        }
      }
    }
  } else {
    unsigned short* dst = sel ? kb : qb;
#pragma unroll
    for (int m = 0; m < 4; ++m) {
      int row0 = bm * 128 + wr * 64 + m * 16 + hi * 4;
#pragma unroll
      for (int n = 0; n < 4; ++n) {
        int d = wc * 64 + n * 16 + lr;  // 0..127 within head
        int dj = d >> 1;
        float sgn = (d & 1) ? 1.f : -1.f;
#pragma unroll
        for (int j = 0; j < 4; ++j) {
          int row = row0 + j;
          int b = row >> 11, s = row & 2047;
          float v = acc[m][n][j];
          float p = __shfl_xor(v, 1);
          float cc = cosT[(s << 6) + dj];
          float sn = sinT[(s << 6) + dj];
          float r = v * cc + sgn * p * sn;
          dst[((size_t)(b * NH + hh) * S_LEN + s) * DHD + d] = f2bf(r);
        }
      }
    }
  }
}

// ---------------- causal flash attention (swapped-QK, in-register softmax) ----
// Q,K,V: [B][H][S][DH] bf16.  O: [B][S][H][DH] bf16.
// S^T = mfma(K,Q): lane holds one q-row (q=lane&15) x 16 kv values
// (kv = 16n + 4*hi + r). V^T stored with kv-permuted columns
// pos(kv)=32*n1+8*h+4*n0+r so PV's A-operand is lane-local packed P.
__global__ __launch_bounds__(256) void k_flash_attn(const unsigned short* __restrict__ Qg,
                                                    const unsigned short* __restrict__ Kg,
                                                    const unsigned short* __restrict__ Vg,
                                                    unsigned short* __restrict__ Og) {
  __shared__ unsigned short K_lds[2][64 * 128];   // [kv][dh], XOR-swizzled slots
  __shared__ unsigned short VT_lds[2][128 * 64];  // [dh][pos(kv)], XOR-swizzled

  const int pq = blockIdx.x, h = blockIdx.y, b = blockIdx.z;
  const int t = threadIdx.x;
  const int lane = t & 63, wave = t >> 6;
  const int hi = lane >> 4, lr = lane & 15;

  const size_t head = (size_t)(b * NH + h) * (size_t)(S_LEN * DHD);
  const unsigned short* Q = Qg + head;
  const unsigned short* Kp = Kg + head;
  const unsigned short* Vp = Vg + head;

  // K staging addressing
  const int kr0 = t >> 4;
  const int kgc = (t & 15) ^ (kr0 & 7);
  const unsigned short* Kbase = Kp + (size_t)kr0 * DHD + kgc * 8;
  const int kdst = t * 16;

  // V staging addressing: vdc = dh-chunk, vsp0 = kv-pair index (kv=2*vsp0)
  const int vdc = t & 15, vsp0 = t >> 4;
  const unsigned short* Vbase = Vp + (size_t)(2 * vsp0) * DHD + vdc * 8;
  // permuted byte offset within a VT row for kv pair (2*vsp0, 2*vsp0+1)
  const int bo0 = 16 * ((vsp0 >> 1) & 3) + 8 * ((vsp0 >> 3) & 1) + 4 * (vsp0 & 1);

  const float sc = 0.08838834764831845f;  // 1/sqrt(128)

  for (int pass = 0; pass < 2; ++pass) {
    const int qt = (pass == 0) ? pq : (31 - pq);
    const int nt = qt + 1;
    const int qbase = qt * 64 + wave * 16;
    const int qrow = qbase + lr;  // this lane's q row (softmax domain)

    bf16x8 qf[4];
    {
      const unsigned short* qr_ = Q + (size_t)(qbase + lr) * DHD;
#pragma unroll
      for (int kc = 0; kc < 4; ++kc) qf[kc] = *(const bf16x8*)(qr_ + kc * 32 + hi * 8);
    }

    f32x4 of[8];
#pragma unroll
    for (int i = 0; i < 8; ++i) {
      f32x4 z = {0.f, 0.f, 0.f, 0.f};
      of[i] = z;
    }
    float mS = -INFINITY;
    float lsum = 0.f;

    // prologue: stage tile 0 into buffer 0
    {
#pragma unroll
      for (int i = 0; i < 4; ++i)
        async_cp16((char*)K_lds[0] + kdst + i * 4096, Kbase + (size_t)(16 * i) * DHD);
      ushort8 va0 = *(const ushort8*)(Vbase);
      ushort8 vb0 = *(const ushort8*)(Vbase + DHD);
      ushort8 va1 = *(const ushort8*)(Vbase + (size_t)32 * DHD);
      ushort8 vb1 = *(const ushort8*)(Vbase + (size_t)33 * DHD);
#pragma unroll
      for (int j = 0; j < 8; ++j) {
        int row = vdc * 8 + j;
        int swz = ((j ^ vdc) & 7) << 4;
        *(unsigned int*)((char*)VT_lds[0] + row * 128 + (bo0 ^ swz)) =
            (unsigned int)va0[j] | ((unsigned int)vb0[j] << 16);
        *(unsigned int*)((char*)VT_lds[0] + row * 128 + ((bo0 | 64) ^ swz)) =
            (unsigned int)va1[j] | ((unsigned int)vb1[j] << 16);
      }
    }
    __syncthreads();

    for (int tt = 0; tt < nt; ++tt) {
      const int cur = tt & 1;
      const int kv0 = tt * 64;
      const bool more = (tt + 1 < nt);
      const bool diag = (tt == qt);

      // issue next tile's loads (K async->LDS, V->regs)
      ushort8 va0, vb0, va1, vb1;
      if (more) {
        const unsigned short* ks = Kbase + (size_t)(kv0 + 64) * DHD;
#pragma unroll
        for (int i = 0; i < 4; ++i)
          async_cp16((char*)K_lds[cur ^ 1] + kdst + i * 4096, ks + (size_t)(16 * i) * DHD);
        const unsigned short* vs = Vbase + (size_t)(kv0 + 64) * DHD;
        va0 = *(const ushort8*)(vs);
        vb0 = *(const ushort8*)(vs + DHD);
        va1 = *(const ushort8*)(vs + (size_t)32 * DHD);
        vb1 = *(const ushort8*)(vs + (size_t)33 * DHD);
      }

      // QK^T swapped: sf[n] = S^T tile, lane: q=lr, kv=kv0+16n+4*hi+reg
      const char* Kb = (const char*)K_lds[cur];
      f32x4 sf[4];
#pragma unroll
      for (int n = 0; n < 4; ++n) {
        f32x4 z = {0.f, 0.f, 0.f, 0.f};
        sf[n] = z;
      }
      __builtin_amdgcn_s_setprio(1);
#pragma unroll
      for (int n = 0; n < 4; ++n) {
        const int kr = n * 16 + lr;
        const int kswz = (kr & 7) << 4;
#pragma unroll
        for (int kc = 0; kc < 4; ++kc) {
          bf16x8 kf = *(const bf16x8*)(Kb + kr * 256 + ((kc * 64 + hi * 16) ^ kswz));
          sf[n] = __builtin_amdgcn_mfma_f32_16x16x32_bf16(kf, qf[kc], sf[n], 0, 0, 0);
        }
      }
      __builtin_amdgcn_s_setprio(0);

      // in-register masked online softmax (per-lane q-row)
      float p[4][4];
      float mx = -INFINITY;
      if (diag) {
#pragma unroll
        for (int n = 0; n < 4; ++n)
#pragma unroll
          for (int j = 0; j < 4; ++j) {
            int kvcol = kv0 + n * 16 + hi * 4 + j;
            float v = (kvcol > qrow) ? -INFINITY : sf[n][j];
            p[n][j] = v;
            mx = fmaxf(mx, v);
          }
      } else {
#pragma unroll
        for (int n = 0; n < 4; ++n)
#pragma unroll
          for (int j = 0; j < 4; ++j) {
            float v = sf[n][j];
            p[n][j] = v;
            mx = fmaxf(mx, v);
          }
      }
      mx = fmaxf(mx, __shfl_xor(mx, 16));
      mx = fmaxf(mx, __shfl_xor(mx, 32));
      float mn = fmaxf(mS, mx);
      float corr = __expf((mS - mn) * sc);
      mS = mn;
      float mns = mn * sc;
      float rs = 0.f;
#pragma unroll
      for (int n = 0; n < 4; ++n)
#pragma unroll
        for (int j = 0; j < 4; ++j) {
          float e = __expf(__builtin_fmaf(p[n][j], sc, -mns));
          p[n][j] = e;
          rs += e;
        }
      rs += __shfl_xor(rs, 16);
      rs += __shfl_xor(rs, 32);
      lsum = lsum * corr + rs;

      // pack P to bf16 (lane-local; feeds PV A-operand directly)
      unsigned int pk[4][2];
#pragma unroll
      for (int n = 0; n < 4; ++n) {
        pk[n][0] = cvt_pk_bf16(p[n][0], p[n][1]);
        pk[n][1] = cvt_pk_bf16(p[n][2], p[n][3]);
      }

      // rescale O: corr for q-row (qbase+hi*4+j) lives in lane (hi*4+j)
      float corrb[4];
#pragma unroll
      for (int j = 0; j < 4; ++j) corrb[j] = __shfl(corr, hi * 4 + j);
#pragma unroll
      for (int nd = 0; nd < 8; ++nd)
#pragma unroll
        for (int j = 0; j < 4; ++j) of[nd][j] *= corrb[j];

      // PV: O[16 q][128 dh] += P * V (V stored kv-permuted, A is lane-local)
      const char* Vb = (const char*)VT_lds[cur];
      __builtin_amdgcn_s_setprio(1);
#pragma unroll
      for (int kc = 0; kc < 2; ++kc) {
        union { unsigned int u[4]; bf16x8 v; } pa;
        pa.u[0] = pk[2 * kc][0];
        pa.u[1] = pk[2 * kc][1];
        pa.u[2] = pk[2 * kc + 1][0];
        pa.u[3] = pk[2 * kc + 1][1];
#pragma unroll
        for (int nd = 0; nd < 8; ++nd) {
          const int vr = nd * 16 + lr;
          const int vswz = ((vr & 7) ^ ((vr >> 3) & 7)) << 4;
          bf16x8 vf = *(const bf16x8*)(Vb + vr * 128 + ((kc * 64 + hi * 16) ^ vswz));
          of[nd] = __builtin_amdgcn_mfma_f32_16x16x32_bf16(pa.v, vf, of[nd], 0, 0, 0);
        }
      }
      __builtin_amdgcn_s_setprio(0);

      // complete next tile's V staging (reg -> LDS, permuted+swizzled)
      if (more) {
        char* Vw = (char*)VT_lds[cur ^ 1];
#pragma unroll
        for (int j = 0; j < 8; ++j) {
          int row = vdc * 8 + j;
          int swz = ((j ^ vdc) & 7) << 4;
          *(unsigned int*)(Vw + row * 128 + (bo0 ^ swz)) =
              (unsigned int)va0[j] | ((unsigned int)vb0[j] << 16);
          *(unsigned int*)(Vw + row * 128 + ((bo0 | 64) ^ swz)) =
              (unsigned int)va1[j] | ((unsigned int)vb1[j] << 16);
        }
      }
      __syncthreads();
    }

    // epilogue: normalize, write [B][S][H][DH]
    float inv[4];
#pragma unroll
    for (int j = 0; j < 4; ++j) {
      float ls = __shfl(lsum, hi * 4 + j);
      inv[j] = 1.0f / ls;
    }
#pragma unroll
    for (int nd = 0; nd < 8; ++nd)
#pragma unroll
      for (int j = 0; j < 4; ++j) {
        int qr = qbase + hi * 4 + j;
        Og[((size_t)(b * S_LEN + qr) * NH + h) * DHD + nd * 16 + lr] = f2bf(of[nd][j] * inv[j]);
      }
  }
}

// ---------------- launch ----------------
extern "C" void kernel_launch(void* const* d_in, const int* in_sizes, int n_in,
                              void* d_out, int out_size, void* d_ws, size_t ws_size,
                              hipStream_t stream) {
  const float* x  = (const float*)d_in[0];
  const float* wq = (const float*)d_in[1];
  const float* wk = (const float*)d_in[2];
  const float* wv = (const float*)d_in[3];
  const float* wo = (const float*)d_in[4];
  float* out = (float*)d_out;

  char* ws = (char*)d_ws;
  unsigned short* xb    = (unsigned short*)(ws);              // 16 MB (reused as attn out)
  unsigned short* wqT   = (unsigned short*)(ws + 16777216);   // 8 MB each, contiguous -> [6144][2048]
  unsigned short* wkT   = (unsigned short*)(ws + 25165824);
  unsigned short* wvT   = (unsigned short*)(ws + 33554432);
  unsigned short* woT   = (unsigned short*)(ws + 41943040);
  unsigned short* qb    = (unsigned short*)(ws + 50331648);   // 16 MB each
  unsigned short* kb    = (unsigned short*)(ws + 67108864);
  unsigned short* vb    = (unsigned short*)(ws + 83886080);
  float*          cosT  = (float*)(ws + 100663296);           // 512 KB
  float*          sinT  = (float*)(ws + 101187584);
  unsigned short* attnb = xb;

  k_cast_bf16<<<8192, 256, 0, stream>>>(x, xb, 2097152);
  dim3 tg(32, 32);
  k_transpose_cast<<<tg, 256, 0, stream>>>(wq, wqT);
  k_transpose_cast<<<tg, 256, 0, stream>>>(wk, wkT);
  k_transpose_cast<<<tg, 256, 0, stream>>>(wv, wvT);
  k_transpose_cast<<<tg, 256, 0, stream>>>(wo, woT);
  k_rope_table<<<512, 256, 0, stream>>>(cosT, sinT);

  // fused q/k/v projection: one GEMM over N=6144, 1536 blocks
  dim3 gqkv(48, 32);
  k_gemm_qkv<<<gqkv, 256, 0, stream>>>(xb, wqT, qb, kb, vb, cosT, sinT);

  dim3 ga(16, 16, 2);  // q-tile pairs, heads, batch
  k_flash_attn<<<ga, 256, 0, stream>>>(qb, kb, vb, attnb);

  dim3 gg(16, 32);  // N/128, M/128
  k_gemm0<<<gg, 256, 0, stream>>>(attnb, woT, out, 4096, 2048, 2048);
}

// Round 4
// 277.902 us; speedup vs baseline: 1.9542x; 1.1150x over previous
//
#include <hip/hip_runtime.h>
#include <hip/hip_bf16.h>
#include <stdint.h>

#define B_SZ   2
#define S_LEN  2048
#define DMODEL 2048
#define NH     16
#define DHD    128

typedef __attribute__((ext_vector_type(8))) __bf16 bf16x8;
typedef __attribute__((ext_vector_type(4))) float  f32x4;
typedef __attribute__((ext_vector_type(4))) float  float4v;
typedef __attribute__((ext_vector_type(8))) unsigned short ushort8;
typedef __attribute__((ext_vector_type(4))) unsigned short ushort4v;

__device__ __forceinline__ unsigned short f2bf(float f) {
  unsigned int u = __float_as_uint(f);
  unsigned int r = (u + 0x7fffu + ((u >> 16) & 1u)) >> 16;
  return (unsigned short)r;
}

__device__ __forceinline__ unsigned int cvt_pk_bf16(float lo, float hi) {
  unsigned int r;
  asm("v_cvt_pk_bf16_f32 %0, %1, %2" : "=v"(r) : "v"(lo), "v"(hi));
  return r;
}

__device__ __forceinline__ void async_cp16(void* lds, const void* g) {
  __builtin_amdgcn_global_load_lds(
      (const __attribute__((address_space(1))) void*)g,
      (__attribute__((address_space(3))) void*)lds, 16, 0, 0);
}

// ---------------- elementwise cast x -> bf16 ----------------
__global__ __launch_bounds__(256) void k_cast_bf16(const float* __restrict__ in,
                                                   unsigned short* __restrict__ out,
                                                   int n4) {
  int i = blockIdx.x * 256 + threadIdx.x;
  if (i >= n4) return;
  float4v v = ((const float4v*)in)[i];
  ushort4v o;
  o[0] = f2bf(v[0]); o[1] = f2bf(v[1]); o[2] = f2bf(v[2]); o[3] = f2bf(v[3]);
  ((ushort4v*)out)[i] = o;
}

// ---------------- transpose + cast W[K][N] -> WT[N][K] bf16 ----------------
__global__ __launch_bounds__(256) void k_transpose_cast(const float* __restrict__ W,
                                                        unsigned short* __restrict__ WT) {
  __shared__ unsigned short tile[64 * 72];
  const int n0 = blockIdx.x * 64;
  const int k0 = blockIdx.y * 64;
  const int t = threadIdx.x;
#pragma unroll
  for (int i = 0; i < 4; ++i) {
    int c = t + 256 * i;
    int r = c >> 4, c4 = c & 15;
    float4v v = *(const float4v*)(W + (size_t)(k0 + r) * DMODEL + n0 + c4 * 4);
    ushort4v o;
    o[0] = f2bf(v[0]); o[1] = f2bf(v[1]); o[2] = f2bf(v[2]); o[3] = f2bf(v[3]);
    *(ushort4v*)(&tile[r * 72 + c4 * 4]) = o;
  }
  __syncthreads();
#pragma unroll
  for (int i = 0; i < 2; ++i) {
    int c = t + 256 * i;
    int n = c >> 3, k8 = c & 7;
    ushort8 o;
#pragma unroll
    for (int j = 0; j < 8; ++j) o[j] = tile[(k8 * 8 + j) * 72 + n];
    *(ushort8*)(WT + (size_t)(n0 + n) * DMODEL + k0 + k8 * 8) = o;
  }
}

// ---------------- rope cos/sin table [S][64] ----------------
__global__ __launch_bounds__(256) void k_rope_table(float* __restrict__ cosT,
                                                    float* __restrict__ sinT) {
  int i = blockIdx.x * 256 + threadIdx.x;  // < S_LEN*64
  int s = i >> 6, dj = i & 63;
  float e = __expf(-9.210340371976184f * (float)dj * (1.0f / 64.0f)); // 10000^{-dj/64}
  float f = (float)s * e;
  cosT[i] = cosf(f);
  sinT[i] = sinf(f);
}

// ---------------- 256x256x64 8-phase GEMM (m201 schedule, plain HIP) -------
// C[M][N] = A[M][K] * BT[N][K]^T, K=2048 fixed (32 K-tiles of 64).
// 8 waves (2M x 4N), per-wave output 128x64, 128 KiB LDS double-buffer.
// LDS per buf: A 32K (4 grps x [2 half][32 r][128B]), B 32K (2 units x [128 r][128B]).
// Byte-slot swizzle slot^=(row&7) applied on read AND on pre-swizzled global src.
// EPI 0: fp32 row-major C0.  EPI 1: fused QKV epilogue (RoPE on q/k), bf16 BHSD.
#define GNT 32

template <int EPI>
__global__ __launch_bounds__(512, 2) void k_gemm256(
    const unsigned short* __restrict__ A,
    const unsigned short* __restrict__ BT,
    float* __restrict__ C0,
    unsigned short* __restrict__ Cq,
    unsigned short* __restrict__ Ck,
    unsigned short* __restrict__ Cv,
    const float* __restrict__ cosT,
    const float* __restrict__ sinT,
    int NBN) {
  __shared__ char smem[131072];
  const int tid = threadIdx.x;

  // XCD-aware block swizzle (grid % 8 == 0 for all our launches)
  const int nwg = gridDim.x;
  const int wg = blockIdx.x;
  const int swz = (wg & 7) * (nwg >> 3) + (wg >> 3);
  const int bn = swz % NBN, bm = swz / NBN;

  // ---- staging addressing (per-thread, 2 chunks of 16B per 16KiB unit) ----
  const int s8 = tid & 7;
  const int r5 = (tid >> 3) & 31;
  const int hf = tid >> 8;
  const int r7 = tid >> 3;                // 0..63
  const int gs = s8 ^ (r7 & 7);           // pre-swizzled global col slot
  const unsigned short* Abase = A + (size_t)(bm * 256 + hf * 128 + r5) * 2048 + gs * 8;
  const unsigned short* Bbase = BT + (size_t)(bn * 256 + r7) * 2048 + gs * 8;
  const int dstA = tid * 16;
  const int dstB = 32768 + tid * 16;

  // ---- fragment addressing ----
  const int lane = tid & 63, wid = tid >> 6;
  const int wr = wid >> 2, wc = wid & 3;
  const int lr = lane & 15, hi = lane >> 4;
  const int cx = (lr & 7) << 4;
  const int ck0 = (hi * 16) ^ cx;         // kstep 0 col bytes (swizzled)
  const int ck1 = (64 + hi * 16) ^ cx;    // kstep 1
  const int aRB = wr * 4096 + lr * 128;
  const int bRB = 32768 + (wc >> 1) * 16384 + ((wc & 1) * 64 + lr) * 128;

  f32x4 acc[8][4];
#pragma unroll
  for (int m = 0; m < 8; ++m)
#pragma unroll
    for (int n = 0; n < 4; ++n) {
      f32x4 z = {0.f, 0.f, 0.f, 0.f};
      acc[m][n] = z;
    }

#define STAGE_A(c, G, t_) do {                                              \
    const unsigned short* _src = Abase + (size_t)(G) * 64 * 2048 + (t_) * 64; \
    async_cp16(smem + (c) * 65536 + (G) * 16384 + dstA, _src);              \
    async_cp16(smem + (c) * 65536 + (G) * 16384 + dstA + 8192, _src + 32 * 2048); \
  } while (0)
#define STAGE_B(c, u, t_) do {                                              \
    const unsigned short* _src = Bbase + (size_t)(u) * 128 * 2048 + (t_) * 64; \
    async_cp16(smem + (c) * 65536 + (u) * 16384 + dstB, _src);              \
    async_cp16(smem + (c) * 65536 + (u) * 16384 + dstB + 8192, _src + 64 * 2048); \
  } while (0)

#define TILEBODY(CC) do {                                                   \
    bf16x8 bfr[4][2];                                                       \
    _Pragma("unroll")                                                       \
    for (int p = 0; p < 4; ++p) {                                           \
      bf16x8 a00 = *(const bf16x8*)(smem + (CC) * 65536 + aRB + p * 8192 + ck0); \
      bf16x8 a01 = *(const bf16x8*)(smem + (CC) * 65536 + aRB + p * 8192 + ck1); \
      bf16x8 a10 = *(const bf16x8*)(smem + (CC) * 65536 + aRB + p * 8192 + 2048 + ck0); \
      bf16x8 a11 = *(const bf16x8*)(smem + (CC) * 65536 + aRB + p * 8192 + 2048 + ck1); \
      if (p == 0) {                                                         \
        _Pragma("unroll")                                                   \
        for (int n = 0; n < 4; ++n) {                                       \
          bfr[n][0] = *(const bf16x8*)(smem + (CC) * 65536 + bRB + n * 2048 + ck0); \
          bfr[n][1] = *(const bf16x8*)(smem + (CC) * 65536 + bRB + n * 2048 + ck1); \
        }                                                                   \
      }                                                                     \
      if (p == 0 && t + 1 < GNT) STAGE_A((CC) ^ 1, 1, t + 1);               \
      if (p == 1 && t + 2 < GNT) STAGE_B(CC, 0, t + 2);                     \
      if (p == 2 && t + 2 < GNT) STAGE_B(CC, 1, t + 2);                     \
      if (p == 3 && t + 2 < GNT) STAGE_A(CC, 0, t + 2);                     \
      __builtin_amdgcn_s_barrier();                                         \
      asm volatile("s_waitcnt lgkmcnt(0)" ::: "memory");                    \
      __builtin_amdgcn_sched_barrier(0);                                    \
      __builtin_amdgcn_s_setprio(1);                                        \
      _Pragma("unroll")                                                     \
      for (int n = 0; n < 4; ++n) {                                         \
        acc[2 * p][n]     = __builtin_amdgcn_mfma_f32_16x16x32_bf16(a00, bfr[n][0], acc[2 * p][n], 0, 0, 0); \
        acc[2 * p][n]     = __builtin_amdgcn_mfma_f32_16x16x32_bf16(a01, bfr[n][1], acc[2 * p][n], 0, 0, 0); \
        acc[2 * p + 1][n] = __builtin_amdgcn_mfma_f32_16x16x32_bf16(a10, bfr[n][0], acc[2 * p + 1][n], 0, 0, 0); \
        acc[2 * p + 1][n] = __builtin_amdgcn_mfma_f32_16x16x32_bf16(a11, bfr[n][1], acc[2 * p + 1][n], 0, 0, 0); \
      }                                                                     \
      __builtin_amdgcn_s_setprio(0);                                        \
      if (p == 3) {                                                         \
        if (t + 2 < GNT) { asm volatile("s_waitcnt vmcnt(6)" ::: "memory"); } \
        else             { asm volatile("s_waitcnt vmcnt(0)" ::: "memory"); } \
      }                                                                     \
      __builtin_amdgcn_s_barrier();                                         \
      __builtin_amdgcn_sched_barrier(0);                                    \
    }                                                                       \
  } while (0)

  // prologue: tile0 (4 units) + tile1 first 3 units; A-g23 of tile1 goes at t0.p0
  STAGE_A(0, 0, 0); STAGE_A(0, 1, 0); STAGE_B(0, 0, 0); STAGE_B(0, 1, 0);
  STAGE_B(1, 0, 1); STAGE_B(1, 1, 1); STAGE_A(1, 0, 1);
  asm volatile("s_waitcnt vmcnt(6)" ::: "memory");
  __builtin_amdgcn_s_barrier();
  __builtin_amdgcn_sched_barrier(0);

  int t;
  for (int it = 0; it < GNT / 2; ++it) {
    t = 2 * it;     TILEBODY(0);
    t = 2 * it + 1; TILEBODY(1);
  }

  // ---- epilogue ----
  const int row_b = bm * 256 + wr * 128 + hi * 4;
  const int col_b = bn * 256 + wc * 64 + lr;
  if (EPI == 0) {
#pragma unroll
    for (int m = 0; m < 8; ++m)
#pragma unroll
      for (int n = 0; n < 4; ++n) {
        int col = col_b + n * 16;
#pragma unroll
        for (int j = 0; j < 4; ++j) {
          int row = row_b + m * 16 + j;
          C0[(size_t)row * 2048 + col] = acc[m][n][j];
        }
      }
  } else {
    const int sel = bn >> 3;  // 0:q 1:k 2:v
#pragma unroll
    for (int m = 0; m < 8; ++m) {
#pragma unroll
      for (int n = 0; n < 4; ++n) {
        int col = col_b + n * 16;
        int hh = (col >> 7) & 15, d = col & 127;
        if (sel == 2) {
#pragma unroll
          for (int j = 0; j < 4; ++j) {
            int row = row_b + m * 16 + j;
            int b = row >> 11, s = row & 2047;
            Cv[((size_t)(b * NH + hh) * S_LEN + s) * DHD + d] = f2bf(acc[m][n][j]);
          }
        } else {
          unsigned short* dst = sel ? Ck : Cq;
          int dj = d >> 1;
          float sgn = (d & 1) ? 1.f : -1.f;
#pragma unroll
          for (int j = 0; j < 4; ++j) {
            int row = row_b + m * 16 + j;
            int b = row >> 11, s = row & 2047;
            float v = acc[m][n][j];
            float pp = __shfl_xor(v, 1);
            float cc = cosT[(s << 6) + dj];
            float sn = sinT[(s << 6) + dj];
            dst[((size_t)(b * NH + hh) * S_LEN + s) * DHD + d] = f2bf(v * cc + sgn * pp * sn);
          }
        }
      }
    }
  }
#undef TILEBODY
#undef STAGE_A
#undef STAGE_B
}

// ---------------- causal flash attention (swapped-QK, in-register softmax) ----
// Q,K,V: [B][H][S][DH] bf16.  O: [B][S][H][DH] bf16.
__global__ __launch_bounds__(256) void k_flash_attn(const unsigned short* __restrict__ Qg,
                                                    const unsigned short* __restrict__ Kg,
                                                    const unsigned short* __restrict__ Vg,
                                                    unsigned short* __restrict__ Og) {
  __shared__ unsigned short K_lds[2][64 * 128];   // [kv][dh], XOR-swizzled slots
  __shared__ unsigned short VT_lds[2][128 * 64];  // [dh][pos(kv)], XOR-swizzled

  const int pq = blockIdx.x, h = blockIdx.y, b = blockIdx.z;
  const int t = threadIdx.x;
  const int lane = t & 63, wave = t >> 6;
  const int hi = lane >> 4, lr = lane & 15;

  const size_t head = (size_t)(b * NH + h) * (size_t)(S_LEN * DHD);
  const unsigned short* Q = Qg + head;
  const unsigned short* Kp = Kg + head;
  const unsigned short* Vp = Vg + head;

  // K staging addressing
  const int kr0 = t >> 4;
  const int kgc = (t & 15) ^ (kr0 & 7);
  const unsigned short* Kbase = Kp + (size_t)kr0 * DHD + kgc * 8;
  const int kdst = t * 16;

  // V staging addressing: vdc = dh-chunk, vsp0 = kv-pair index (kv=2*vsp0)
  const int vdc = t & 15, vsp0 = t >> 4;
  const unsigned short* Vbase = Vp + (size_t)(2 * vsp0) * DHD + vdc * 8;
  // permuted byte offset within a VT row for kv pair (2*vsp0, 2*vsp0+1)
  const int bo0 = 16 * ((vsp0 >> 1) & 3) + 8 * ((vsp0 >> 3) & 1) + 4 * (vsp0 & 1);

  const float sc = 0.08838834764831845f;  // 1/sqrt(128)

  for (int pass = 0; pass < 2; ++pass) {
    const int qt = (pass == 0) ? pq : (31 - pq);
    const int nt = qt + 1;
    const int qbase = qt * 64 + wave * 16;
    const int qrow = qbase + lr;  // this lane's q row (softmax domain)

    bf16x8 qf[4];
    {
      const unsigned short* qr_ = Q + (size_t)(qbase + lr) * DHD;
#pragma unroll
      for (int kc = 0; kc < 4; ++kc) qf[kc] = *(const bf16x8*)(qr_ + kc * 32 + hi * 8);
    }

    f32x4 of[8];
#pragma unroll
    for (int i = 0; i < 8; ++i) {
      f32x4 z = {0.f, 0.f, 0.f, 0.f};
      of[i] = z;
    }
    float mS = -INFINITY;
    float lsum = 0.f;

    // prologue: stage tile 0 into buffer 0
    {
#pragma unroll
      for (int i = 0; i < 4; ++i)
        async_cp16((char*)K_lds[0] + kdst + i * 4096, Kbase + (size_t)(16 * i) * DHD);
      ushort8 va0 = *(const ushort8*)(Vbase);
      ushort8 vb0 = *(const ushort8*)(Vbase + DHD);
      ushort8 va1 = *(const ushort8*)(Vbase + (size_t)32 * DHD);
      ushort8 vb1 = *(const ushort8*)(Vbase + (size_t)33 * DHD);
#pragma unroll
      for (int j = 0; j < 8; ++j) {
        int row = vdc * 8 + j;
        int swz = ((j ^ vdc) & 7) << 4;
        *(unsigned int*)((char*)VT_lds[0] + row * 128 + (bo0 ^ swz)) =
            (unsigned int)va0[j] | ((unsigned int)vb0[j] << 16);
        *(unsigned int*)((char*)VT_lds[0] + row * 128 + ((bo0 | 64) ^ swz)) =
            (unsigned int)va1[j] | ((unsigned int)vb1[j] << 16);
      }
    }
    __syncthreads();

    for (int tt = 0; tt < nt; ++tt) {
      const int cur = tt & 1;
      const int kv0 = tt * 64;
      const bool more = (tt + 1 < nt);
      const bool diag = (tt == qt);

      // issue next tile's loads (K async->LDS, V->regs)
      ushort8 va0, vb0, va1, vb1;
      if (more) {
        const unsigned short* ks = Kbase + (size_t)(kv0 + 64) * DHD;
#pragma unroll
        for (int i = 0; i < 4; ++i)
          async_cp16((char*)K_lds[cur ^ 1] + kdst + i * 4096, ks + (size_t)(16 * i) * DHD);
        const unsigned short* vs = Vbase + (size_t)(kv0 + 64) * DHD;
        va0 = *(const ushort8*)(vs);
        vb0 = *(const ushort8*)(vs + DHD);
        va1 = *(const ushort8*)(vs + (size_t)32 * DHD);
        vb1 = *(const ushort8*)(vs + (size_t)33 * DHD);
      }

      // QK^T swapped: sf[n] = S^T tile, lane: q=lr, kv=kv0+16n+4*hi+reg
      const char* Kb = (const char*)K_lds[cur];
      f32x4 sf[4];
#pragma unroll
      for (int n = 0; n < 4; ++n) {
        f32x4 z = {0.f, 0.f, 0.f, 0.f};
        sf[n] = z;
      }
      __builtin_amdgcn_s_setprio(1);
#pragma unroll
      for (int n = 0; n < 4; ++n) {
        const int kr = n * 16 + lr;
        const int kswz = (kr & 7) << 4;
#pragma unroll
        for (int kc = 0; kc < 4; ++kc) {
          bf16x8 kf = *(const bf16x8*)(Kb + kr * 256 + ((kc * 64 + hi * 16) ^ kswz));
          sf[n] = __builtin_amdgcn_mfma_f32_16x16x32_bf16(kf, qf[kc], sf[n], 0, 0, 0);
        }
      }
      __builtin_amdgcn_s_setprio(0);

      // in-register masked online softmax (per-lane q-row)
      float p[4][4];
      float mx = -INFINITY;
      if (diag) {
#pragma unroll
        for (int n = 0; n < 4; ++n)
#pragma unroll
          for (int j = 0; j < 4; ++j) {
            int kvcol = kv0 + n * 16 + hi * 4 + j;
            float v = (kvcol > qrow) ? -INFINITY : sf[n][j];
            p[n][j] = v;
            mx = fmaxf(mx, v);
          }
      } else {
#pragma unroll
        for (int n = 0; n < 4; ++n)
#pragma unroll
          for (int j = 0; j < 4; ++j) {
            float v = sf[n][j];
            p[n][j] = v;
            mx = fmaxf(mx, v);
          }
      }
      mx = fmaxf(mx, __shfl_xor(mx, 16));
      mx = fmaxf(mx, __shfl_xor(mx, 32));
      float mn = fmaxf(mS, mx);
      float corr = __expf((mS - mn) * sc);
      mS = mn;
      float mns = mn * sc;
      float rs = 0.f;
#pragma unroll
      for (int n = 0; n < 4; ++n)
#pragma unroll
        for (int j = 0; j < 4; ++j) {
          float e = __expf(__builtin_fmaf(p[n][j], sc, -mns));
          p[n][j] = e;
          rs += e;
        }
      rs += __shfl_xor(rs, 16);
      rs += __shfl_xor(rs, 32);
      lsum = lsum * corr + rs;

      // pack P to bf16 (lane-local; feeds PV A-operand directly)
      unsigned int pk[4][2];
#pragma unroll
      for (int n = 0; n < 4; ++n) {
        pk[n][0] = cvt_pk_bf16(p[n][0], p[n][1]);
        pk[n][1] = cvt_pk_bf16(p[n][2], p[n][3]);
      }

      // rescale O: corr for q-row (qbase+hi*4+j) lives in lane (hi*4+j)
      float corrb[4];
#pragma unroll
      for (int j = 0; j < 4; ++j) corrb[j] = __shfl(corr, hi * 4 + j);
#pragma unroll
      for (int nd = 0; nd < 8; ++nd)
#pragma unroll
        for (int j = 0; j < 4; ++j) of[nd][j] *= corrb[j];

      // PV: O[16 q][128 dh] += P * V (V stored kv-permuted, A is lane-local)
      const char* Vb = (const char*)VT_lds[cur];
      __builtin_amdgcn_s_setprio(1);
#pragma unroll
      for (int kc = 0; kc < 2; ++kc) {
        union { unsigned int u[4]; bf16x8 v; } pa;
        pa.u[0] = pk[2 * kc][0];
        pa.u[1] = pk[2 * kc][1];
        pa.u[2] = pk[2 * kc + 1][0];
        pa.u[3] = pk[2 * kc + 1][1];
#pragma unroll
        for (int nd = 0; nd < 8; ++nd) {
          const int vr = nd * 16 + lr;
          const int vswz = ((vr & 7) ^ ((vr >> 3) & 7)) << 4;
          bf16x8 vf = *(const bf16x8*)(Vb + vr * 128 + ((kc * 64 + hi * 16) ^ vswz));
          of[nd] = __builtin_amdgcn_mfma_f32_16x16x32_bf16(pa.v, vf, of[nd], 0, 0, 0);
        }
      }
      __builtin_amdgcn_s_setprio(0);

      // complete next tile's V staging (reg -> LDS, permuted+swizzled)
      if (more) {
        char* Vw = (char*)VT_lds[cur ^ 1];
#pragma unroll
        for (int j = 0; j < 8; ++j) {
          int row = vdc * 8 + j;
          int swz = ((j ^ vdc) & 7) << 4;
          *(unsigned int*)(Vw + row * 128 + (bo0 ^ swz)) =
              (unsigned int)va0[j] | ((unsigned int)vb0[j] << 16);
          *(unsigned int*)(Vw + row * 128 + ((bo0 | 64) ^ swz)) =
              (unsigned int)va1[j] | ((unsigned int)vb1[j] << 16);
        }
      }
      __syncthreads();
    }

    // epilogue: normalize, write [B][S][H][DH]
    float inv[4];
#pragma unroll
    for (int j = 0; j < 4; ++j) {
      float ls = __shfl(lsum, hi * 4 + j);
      inv[j] = 1.0f / ls;
    }
#pragma unroll
    for (int nd = 0; nd < 8; ++nd)
#pragma unroll
      for (int j = 0; j < 4; ++j) {
        int qr = qbase + hi * 4 + j;
        Og[((size_t)(b * S_LEN + qr) * NH + h) * DHD + nd * 16 + lr] = f2bf(of[nd][j] * inv[j]);
      }
  }
}

// ---------------- launch ----------------
extern "C" void kernel_launch(void* const* d_in, const int* in_sizes, int n_in,
                              void* d_out, int out_size, void* d_ws, size_t ws_size,
                              hipStream_t stream) {
  const float* x  = (const float*)d_in[0];
  const float* wq = (const float*)d_in[1];
  const float* wk = (const float*)d_in[2];
  const float* wv = (const float*)d_in[3];
  const float* wo = (const float*)d_in[4];
  float* out = (float*)d_out;

  char* ws = (char*)d_ws;
  unsigned short* xb    = (unsigned short*)(ws);              // 16 MB (reused as attn out)
  unsigned short* wqT   = (unsigned short*)(ws + 16777216);   // 8 MB each, contiguous -> [6144][2048]
  unsigned short* wkT   = (unsigned short*)(ws + 25165824);
  unsigned short* wvT   = (unsigned short*)(ws + 33554432);
  unsigned short* woT   = (unsigned short*)(ws + 41943040);
  unsigned short* qb    = (unsigned short*)(ws + 50331648);   // 16 MB each
  unsigned short* kb    = (unsigned short*)(ws + 67108864);
  unsigned short* vb    = (unsigned short*)(ws + 83886080);
  float*          cosT  = (float*)(ws + 100663296);           // 512 KB
  float*          sinT  = (float*)(ws + 101187584);
  unsigned short* attnb = xb;

  k_cast_bf16<<<8192, 256, 0, stream>>>(x, xb, 2097152);
  dim3 tg(32, 32);
  k_transpose_cast<<<tg, 256, 0, stream>>>(wq, wqT);
  k_transpose_cast<<<tg, 256, 0, stream>>>(wk, wkT);
  k_transpose_cast<<<tg, 256, 0, stream>>>(wv, wvT);
  k_transpose_cast<<<tg, 256, 0, stream>>>(wo, woT);
  k_rope_table<<<512, 256, 0, stream>>>(cosT, sinT);

  // fused q/k/v projection: 256^2 tiles over N=6144 -> 16x24 = 384 blocks
  k_gemm256<1><<<384, 512, 0, stream>>>(xb, wqT, nullptr, qb, kb, vb, cosT, sinT, 24);

  dim3 ga(16, 16, 2);  // q-tile pairs, heads, batch
  k_flash_attn<<<ga, 256, 0, stream>>>(qb, kb, vb, attnb);

  // output projection: 16x8 = 128 blocks
  k_gemm256<0><<<128, 512, 0, stream>>>(attnb, woT, out, nullptr, nullptr, nullptr,
                                        nullptr, nullptr, 8);
}

// Round 5
// 240.465 us; speedup vs baseline: 2.2585x; 1.1557x over previous
//
#include <hip/hip_runtime.h>
#include <hip/hip_bf16.h>
#include <stdint.h>

#define B_SZ   2
#define S_LEN  2048
#define DMODEL 2048
#define NH     16
#define DHD    128

typedef __attribute__((ext_vector_type(8))) __bf16 bf16x8;
typedef __attribute__((ext_vector_type(4))) float  f32x4;
typedef __attribute__((ext_vector_type(4))) float  float4v;
typedef __attribute__((ext_vector_type(8))) unsigned short ushort8;
typedef __attribute__((ext_vector_type(4))) unsigned short ushort4v;

__device__ __forceinline__ unsigned short f2bf(float f) {
  unsigned int u = __float_as_uint(f);
  unsigned int r = (u + 0x7fffu + ((u >> 16) & 1u)) >> 16;
  return (unsigned short)r;
}

__device__ __forceinline__ unsigned int cvt_pk_bf16(float lo, float hi) {
  unsigned int r;
  asm("v_cvt_pk_bf16_f32 %0, %1, %2" : "=v"(r) : "v"(lo), "v"(hi));
  return r;
}

__device__ __forceinline__ void async_cp16(void* lds, const void* g) {
  __builtin_amdgcn_global_load_lds(
      (const __attribute__((address_space(1))) void*)g,
      (__attribute__((address_space(3))) void*)lds, 16, 0, 0);
}

// ---------------- elementwise cast x -> bf16 ----------------
__global__ __launch_bounds__(256) void k_cast_bf16(const float* __restrict__ in,
                                                   unsigned short* __restrict__ out,
                                                   int n4) {
  int i = blockIdx.x * 256 + threadIdx.x;
  if (i >= n4) return;
  float4v v = ((const float4v*)in)[i];
  ushort4v o;
  o[0] = f2bf(v[0]); o[1] = f2bf(v[1]); o[2] = f2bf(v[2]); o[3] = f2bf(v[3]);
  ((ushort4v*)out)[i] = o;
}

// ---- transpose + cast all four weights: W[K][N] -> WT[N][K] bf16 (z-batched) ----
__global__ __launch_bounds__(256) void k_transpose_all(const float* __restrict__ w0,
                                                       const float* __restrict__ w1,
                                                       const float* __restrict__ w2,
                                                       const float* __restrict__ w3,
                                                       unsigned short* __restrict__ WTbase) {
  __shared__ unsigned short tile[64 * 72];
  const int z = blockIdx.z;
  const float* W = (z == 0) ? w0 : (z == 1) ? w1 : (z == 2) ? w2 : w3;
  unsigned short* WT = WTbase + (size_t)z * 4194304;
  const int n0 = blockIdx.x * 64;
  const int k0 = blockIdx.y * 64;
  const int t = threadIdx.x;
#pragma unroll
  for (int i = 0; i < 4; ++i) {
    int c = t + 256 * i;
    int r = c >> 4, c4 = c & 15;
    float4v v = *(const float4v*)(W + (size_t)(k0 + r) * DMODEL + n0 + c4 * 4);
    ushort4v o;
    o[0] = f2bf(v[0]); o[1] = f2bf(v[1]); o[2] = f2bf(v[2]); o[3] = f2bf(v[3]);
    *(ushort4v*)(&tile[r * 72 + c4 * 4]) = o;
  }
  __syncthreads();
#pragma unroll
  for (int i = 0; i < 2; ++i) {
    int c = t + 256 * i;
    int n = c >> 3, k8 = c & 7;
    ushort8 o;
#pragma unroll
    for (int j = 0; j < 8; ++j) o[j] = tile[(k8 * 8 + j) * 72 + n];
    *(ushort8*)(WT + (size_t)(n0 + n) * DMODEL + k0 + k8 * 8) = o;
  }
}

// ---------------- rope cos/sin table [S][64] ----------------
__global__ __launch_bounds__(256) void k_rope_table(float* __restrict__ cosT,
                                                    float* __restrict__ sinT) {
  int i = blockIdx.x * 256 + threadIdx.x;  // < S_LEN*64
  int s = i >> 6, dj = i & 63;
  float e = __expf(-9.210340371976184f * (float)dj * (1.0f / 64.0f)); // 10000^{-dj/64}
  float f = (float)s * e;
  cosT[i] = cosf(f);
  sinT[i] = sinf(f);
}

// ---------------- 128x256x64 2-phase look-ahead GEMM ----------------
// C[M=4096][N] = A[M][2048] * BT[N][2048]^T. 512 thr, 8 waves (2M x 4N),
// per-wave 64x64. LDS 96 KiB: per buf {A 16K, B 32K}, byte-slot swizzle
// slot^=(row&7) (inverse-preswizzled global source, linear gload_lds dest).
// Per tile: p0 issues k0+k1 frag reads (lgkmcnt(8) -> k1 hides under MFMA),
// stages A(t+1); p1 zero-read, stages B(t+2), vmcnt(4). 2 barriers/tile.
// 2-D XCD chunk swizzle: xcd -> 16bm x chn bn rectangle.
// EPI 0: fp32 row-major.  EPI 1: fused QKV epilogue (RoPE on q/k), bf16 BHSD.
template <int EPI>
__global__ __launch_bounds__(512, 2) void k_gemm128(
    const unsigned short* __restrict__ A,
    const unsigned short* __restrict__ BT,
    float* __restrict__ C0,
    unsigned short* __restrict__ Cq,
    unsigned short* __restrict__ Ck,
    unsigned short* __restrict__ Cv,
    const float* __restrict__ cosT,
    const float* __restrict__ sinT,
    int chn) {
  __shared__ char smem[98304];
  const int tid = threadIdx.x;

  // 2-D XCD chunk swizzle: 8 XCDs as 2 (bm) x 4 (bn); chunk = 16bm x chn bn
  const int xcd = blockIdx.x & 7;
  const int idx = blockIdx.x >> 3;           // [0, 16*chn)
  const int bm = (xcd >> 2) * 16 + (idx & 15);
  const int bn = (xcd & 3) * chn + (idx >> 4);

  // ---- staging addressing ----
  const int gs = (tid & 7) ^ ((tid >> 3) & 7);
  const unsigned short* Abase = A + (size_t)(bm * 128 + (tid >> 3)) * 2048 + gs * 8;
  const unsigned short* Bbase = BT + (size_t)(bn * 256 + (tid >> 3)) * 2048 + gs * 8;
  const int dstA = tid * 16;
  const int dstB = 16384 + tid * 16;

  // ---- fragment addressing ----
  const int lane = tid & 63, wid = tid >> 6;
  const int wr = wid >> 2, wcn = wid & 3;
  const int lr = lane & 15, hi = lane >> 4;
  int aoff[4][2], boff[4][2];
#pragma unroll
  for (int m = 0; m < 4; ++m) {
    int row = wr * 64 + m * 16 + lr;
#pragma unroll
    for (int k = 0; k < 2; ++k)
      aoff[m][k] = row * 128 + ((((k * 4 + hi)) ^ (row & 7)) << 4);
  }
#pragma unroll
  for (int n = 0; n < 4; ++n) {
    int row = wcn * 64 + n * 16 + lr;
#pragma unroll
    for (int k = 0; k < 2; ++k)
      boff[n][k] = 16384 + row * 128 + ((((k * 4 + hi)) ^ (row & 7)) << 4);
  }

  f32x4 acc[4][4];
#pragma unroll
  for (int m = 0; m < 4; ++m)
#pragma unroll
    for (int n = 0; n < 4; ++n) {
      f32x4 z = {0.f, 0.f, 0.f, 0.f};
      acc[m][n] = z;
    }

#define STG_A(c, t_) do {                                                   \
    const unsigned short* _s = Abase + (t_) * 64;                           \
    async_cp16(smem + (c) * 49152 + dstA, _s);                              \
    async_cp16(smem + (c) * 49152 + dstA + 8192, _s + 64 * 2048);           \
  } while (0)
#define STG_B(c, t_) do {                                                   \
    const unsigned short* _s = Bbase + (t_) * 64;                           \
    async_cp16(smem + (c) * 49152 + dstB, _s);                              \
    async_cp16(smem + (c) * 49152 + dstB + 8192, _s + 64 * 2048);           \
    async_cp16(smem + (c) * 49152 + dstB + 16384, _s + 128 * 2048);         \
    async_cp16(smem + (c) * 49152 + dstB + 24576, _s + 192 * 2048);         \
  } while (0)

  auto tile = [&](int T, int CC, bool DO_A, bool DO_B, int VM) __attribute__((always_inline)) {
    const char* Sb = smem + CC * 49152;
    bf16x8 a0[4], b0[4], a1[4], b1[4];
    // p0: current-kstep reads first, then look-ahead kstep1
#pragma unroll
    for (int m = 0; m < 4; ++m) a0[m] = *(const bf16x8*)(Sb + aoff[m][0]);
#pragma unroll
    for (int n = 0; n < 4; ++n) b0[n] = *(const bf16x8*)(Sb + boff[n][0]);
    __builtin_amdgcn_sched_barrier(0);
#pragma unroll
    for (int m = 0; m < 4; ++m) a1[m] = *(const bf16x8*)(Sb + aoff[m][1]);
#pragma unroll
    for (int n = 0; n < 4; ++n) b1[n] = *(const bf16x8*)(Sb + boff[n][1]);
    if (DO_A) STG_A(CC ^ 1, T + 1);
    asm volatile("s_waitcnt lgkmcnt(8)" ::: "memory");
    __builtin_amdgcn_sched_barrier(0);
    __builtin_amdgcn_s_setprio(1);
#pragma unroll
    for (int m = 0; m < 4; ++m)
#pragma unroll
      for (int n = 0; n < 4; ++n)
        acc[m][n] = __builtin_amdgcn_mfma_f32_16x16x32_bf16(a0[m], b0[n], acc[m][n], 0, 0, 0);
    __builtin_amdgcn_s_setprio(0);
    __builtin_amdgcn_s_barrier();
    __builtin_amdgcn_sched_barrier(0);
    // p1: no LDS reads; k1 frags already in regs
    asm volatile("s_waitcnt lgkmcnt(0)" ::: "memory");
    __builtin_amdgcn_sched_barrier(0);
    if (DO_B) STG_B(CC, T + 2);
    __builtin_amdgcn_s_setprio(1);
#pragma unroll
    for (int m = 0; m < 4; ++m)
#pragma unroll
      for (int n = 0; n < 4; ++n)
        acc[m][n] = __builtin_amdgcn_mfma_f32_16x16x32_bf16(a1[m], b1[n], acc[m][n], 0, 0, 0);
    __builtin_amdgcn_s_setprio(0);
    if (VM == 0) asm volatile("s_waitcnt vmcnt(4)" ::: "memory");
    else if (VM == 1) asm volatile("s_waitcnt vmcnt(0)" ::: "memory");
    if (VM != 2) {
      __builtin_amdgcn_s_barrier();
      __builtin_amdgcn_sched_barrier(0);
    }
  };

  // prologue: B(0), A(0), B(1); wait for tile-0 units (4 newer in flight)
  STG_B(0, 0);
  STG_A(0, 0);
  STG_B(1, 1);
  asm volatile("s_waitcnt vmcnt(4)" ::: "memory");
  __builtin_amdgcn_s_barrier();
  __builtin_amdgcn_sched_barrier(0);

  for (int it = 0; it < 15; ++it) {
    tile(2 * it, 0, true, true, 0);
    tile(2 * it + 1, 1, true, true, 0);
  }
  tile(30, 0, true, false, 1);
  tile(31, 1, false, false, 2);

  // ---- epilogue ----
  const int row_b = bm * 128 + wr * 64 + hi * 4;
  const int col_b = bn * 256 + wcn * 64 + lr;
  if (EPI == 0) {
#pragma unroll
    for (int m = 0; m < 4; ++m)
#pragma unroll
      for (int n = 0; n < 4; ++n) {
        int col = col_b + n * 16;
#pragma unroll
        for (int j = 0; j < 4; ++j) {
          int row = row_b + m * 16 + j;
          C0[(size_t)row * 2048 + col] = acc[m][n][j];
        }
      }
  } else {
    const int sel = bn >> 3;  // 0:q 1:k 2:v (2048-wide each)
#pragma unroll
    for (int m = 0; m < 4; ++m) {
#pragma unroll
      for (int n = 0; n < 4; ++n) {
        int col = col_b + n * 16;
        int hh = (col >> 7) & 15, d = col & 127;
        if (sel == 2) {
#pragma unroll
          for (int j = 0; j < 4; ++j) {
            int row = row_b + m * 16 + j;
            int b = row >> 11, s = row & 2047;
            Cv[((size_t)(b * NH + hh) * S_LEN + s) * DHD + d] = f2bf(acc[m][n][j]);
          }
        } else {
          unsigned short* dst = sel ? Ck : Cq;
          int dj = d >> 1;
          float sgn = (d & 1) ? 1.f : -1.f;
#pragma unroll
          for (int j = 0; j < 4; ++j) {
            int row = row_b + m * 16 + j;
            int b = row >> 11, s = row & 2047;
            float v = acc[m][n][j];
            float pp = __shfl_xor(v, 1);
            float cc = cosT[(s << 6) + dj];
            float sn = sinT[(s << 6) + dj];
            dst[((size_t)(b * NH + hh) * S_LEN + s) * DHD + d] = f2bf(v * cc + sgn * pp * sn);
          }
        }
      }
    }
  }
#undef STG_A
#undef STG_B
}

// ---------------- causal flash attention (swapped-QK, in-register softmax) ----
// Q,K,V: [B][H][S][DH] bf16.  O: [B][S][H][DH] bf16.
__global__ __launch_bounds__(256) void k_flash_attn(const unsigned short* __restrict__ Qg,
                                                    const unsigned short* __restrict__ Kg,
                                                    const unsigned short* __restrict__ Vg,
                                                    unsigned short* __restrict__ Og) {
  __shared__ unsigned short K_lds[2][64 * 128];   // [kv][dh], XOR-swizzled slots
  __shared__ unsigned short VT_lds[2][128 * 64];  // [dh][pos(kv)], XOR-swizzled

  const int pq = blockIdx.x, h = blockIdx.y, b = blockIdx.z;
  const int t = threadIdx.x;
  const int lane = t & 63, wave = t >> 6;
  const int hi = lane >> 4, lr = lane & 15;

  const size_t head = (size_t)(b * NH + h) * (size_t)(S_LEN * DHD);
  const unsigned short* Q = Qg + head;
  const unsigned short* Kp = Kg + head;
  const unsigned short* Vp = Vg + head;

  // K staging addressing
  const int kr0 = t >> 4;
  const int kgc = (t & 15) ^ (kr0 & 7);
  const unsigned short* Kbase = Kp + (size_t)kr0 * DHD + kgc * 8;
  const int kdst = t * 16;

  // V staging addressing: vdc = dh-chunk, vsp0 = kv-pair index (kv=2*vsp0)
  const int vdc = t & 15, vsp0 = t >> 4;
  const unsigned short* Vbase = Vp + (size_t)(2 * vsp0) * DHD + vdc * 8;
  // permuted byte offset within a VT row for kv pair (2*vsp0, 2*vsp0+1)
  const int bo0 = 16 * ((vsp0 >> 1) & 3) + 8 * ((vsp0 >> 3) & 1) + 4 * (vsp0 & 1);

  const float sc = 0.08838834764831845f;  // 1/sqrt(128)

  for (int pass = 0; pass < 2; ++pass) {
    const int qt = (pass == 0) ? pq : (31 - pq);
    const int nt = qt + 1;
    const int qbase = qt * 64 + wave * 16;
    const int qrow = qbase + lr;  // this lane's q row (softmax domain)

    bf16x8 qf[4];
    {
      const unsigned short* qr_ = Q + (size_t)(qbase + lr) * DHD;
#pragma unroll
      for (int kc = 0; kc < 4; ++kc) qf[kc] = *(const bf16x8*)(qr_ + kc * 32 + hi * 8);
    }

    f32x4 of[8];
#pragma unroll
    for (int i = 0; i < 8; ++i) {
      f32x4 z = {0.f, 0.f, 0.f, 0.f};
      of[i] = z;
    }
    float mS = -INFINITY;
    float lsum = 0.f;

    // prologue: stage tile 0 into buffer 0
    {
#pragma unroll
      for (int i = 0; i < 4; ++i)
        async_cp16((char*)K_lds[0] + kdst + i * 4096, Kbase + (size_t)(16 * i) * DHD);
      ushort8 va0 = *(const ushort8*)(Vbase);
      ushort8 vb0 = *(const ushort8*)(Vbase + DHD);
      ushort8 va1 = *(const ushort8*)(Vbase + (size_t)32 * DHD);
      ushort8 vb1 = *(const ushort8*)(Vbase + (size_t)33 * DHD);
#pragma unroll
      for (int j = 0; j < 8; ++j) {
        int row = vdc * 8 + j;
        int swz = ((j ^ vdc) & 7) << 4;
        *(unsigned int*)((char*)VT_lds[0] + row * 128 + (bo0 ^ swz)) =
            (unsigned int)va0[j] | ((unsigned int)vb0[j] << 16);
        *(unsigned int*)((char*)VT_lds[0] + row * 128 + ((bo0 | 64) ^ swz)) =
            (unsigned int)va1[j] | ((unsigned int)vb1[j] << 16);
      }
    }
    __syncthreads();

    for (int tt = 0; tt < nt; ++tt) {
      const int cur = tt & 1;
      const int kv0 = tt * 64;
      const bool more = (tt + 1 < nt);
      const bool diag = (tt == qt);

      // issue next tile's loads (K async->LDS, V->regs)
      ushort8 va0, vb0, va1, vb1;
      if (more) {
        const unsigned short* ks = Kbase + (size_t)(kv0 + 64) * DHD;
#pragma unroll
        for (int i = 0; i < 4; ++i)
          async_cp16((char*)K_lds[cur ^ 1] + kdst + i * 4096, ks + (size_t)(16 * i) * DHD);
        const unsigned short* vs = Vbase + (size_t)(kv0 + 64) * DHD;
        va0 = *(const ushort8*)(vs);
        vb0 = *(const ushort8*)(vs + DHD);
        va1 = *(const ushort8*)(vs + (size_t)32 * DHD);
        vb1 = *(const ushort8*)(vs + (size_t)33 * DHD);
      }

      // QK^T swapped: sf[n] = S^T tile, lane: q=lr, kv=kv0+16n+4*hi+reg
      const char* Kb = (const char*)K_lds[cur];
      f32x4 sf[4];
#pragma unroll
      for (int n = 0; n < 4; ++n) {
        f32x4 z = {0.f, 0.f, 0.f, 0.f};
        sf[n] = z;
      }
      __builtin_amdgcn_s_setprio(1);
#pragma unroll
      for (int n = 0; n < 4; ++n) {
        const int kr = n * 16 + lr;
        const int kswz = (kr & 7) << 4;
#pragma unroll
        for (int kc = 0; kc < 4; ++kc) {
          bf16x8 kf = *(const bf16x8*)(Kb + kr * 256 + ((kc * 64 + hi * 16) ^ kswz));
          sf[n] = __builtin_amdgcn_mfma_f32_16x16x32_bf16(kf, qf[kc], sf[n], 0, 0, 0);
        }
      }
      __builtin_amdgcn_s_setprio(0);

      // in-register masked online softmax (per-lane q-row)
      float p[4][4];
      float mx = -INFINITY;
      if (diag) {
#pragma unroll
        for (int n = 0; n < 4; ++n)
#pragma unroll
          for (int j = 0; j < 4; ++j) {
            int kvcol = kv0 + n * 16 + hi * 4 + j;
            float v = (kvcol > qrow) ? -INFINITY : sf[n][j];
            p[n][j] = v;
            mx = fmaxf(mx, v);
          }
      } else {
#pragma unroll
        for (int n = 0; n < 4; ++n)
#pragma unroll
          for (int j = 0; j < 4; ++j) {
            float v = sf[n][j];
            p[n][j] = v;
            mx = fmaxf(mx, v);
          }
      }
      mx = fmaxf(mx, __shfl_xor(mx, 16));
      mx = fmaxf(mx, __shfl_xor(mx, 32));
      float mn = fmaxf(mS, mx);
      float corr = __expf((mS - mn) * sc);
      mS = mn;
      float mns = mn * sc;
      float rs = 0.f;
#pragma unroll
      for (int n = 0; n < 4; ++n)
#pragma unroll
        for (int j = 0; j < 4; ++j) {
          float e = __expf(__builtin_fmaf(p[n][j], sc, -mns));
          p[n][j] = e;
          rs += e;
        }
      rs += __shfl_xor(rs, 16);
      rs += __shfl_xor(rs, 32);
      lsum = lsum * corr + rs;

      // pack P to bf16 (lane-local; feeds PV A-operand directly)
      unsigned int pk[4][2];
#pragma unroll
      for (int n = 0; n < 4; ++n) {
        pk[n][0] = cvt_pk_bf16(p[n][0], p[n][1]);
        pk[n][1] = cvt_pk_bf16(p[n][2], p[n][3]);
      }

      // rescale O: corr for q-row (qbase+hi*4+j) lives in lane (hi*4+j)
      float corrb[4];
#pragma unroll
      for (int j = 0; j < 4; ++j) corrb[j] = __shfl(corr, hi * 4 + j);
#pragma unroll
      for (int nd = 0; nd < 8; ++nd)
#pragma unroll
        for (int j = 0; j < 4; ++j) of[nd][j] *= corrb[j];

      // PV: O[16 q][128 dh] += P * V (V stored kv-permuted, A is lane-local)
      const char* Vb = (const char*)VT_lds[cur];
      __builtin_amdgcn_s_setprio(1);
#pragma unroll
      for (int kc = 0; kc < 2; ++kc) {
        union { unsigned int u[4]; bf16x8 v; } pa;
        pa.u[0] = pk[2 * kc][0];
        pa.u[1] = pk[2 * kc][1];
        pa.u[2] = pk[2 * kc + 1][0];
        pa.u[3] = pk[2 * kc + 1][1];
#pragma unroll
        for (int nd = 0; nd < 8; ++nd) {
          const int vr = nd * 16 + lr;
          const int vswz = ((vr & 7) ^ ((vr >> 3) & 7)) << 4;
          bf16x8 vf = *(const bf16x8*)(Vb + vr * 128 + ((kc * 64 + hi * 16) ^ vswz));
          of[nd] = __builtin_amdgcn_mfma_f32_16x16x32_bf16(pa.v, vf, of[nd], 0, 0, 0);
        }
      }
      __builtin_amdgcn_s_setprio(0);

      // complete next tile's V staging (reg -> LDS, permuted+swizzled)
      if (more) {
        char* Vw = (char*)VT_lds[cur ^ 1];
#pragma unroll
        for (int j = 0; j < 8; ++j) {
          int row = vdc * 8 + j;
          int swz = ((j ^ vdc) & 7) << 4;
          *(unsigned int*)(Vw + row * 128 + (bo0 ^ swz)) =
              (unsigned int)va0[j] | ((unsigned int)vb0[j] << 16);
          *(unsigned int*)(Vw + row * 128 + ((bo0 | 64) ^ swz)) =
              (unsigned int)va1[j] | ((unsigned int)vb1[j] << 16);
        }
      }
      __syncthreads();
    }

    // epilogue: normalize, write [B][S][H][DH]
    float inv[4];
#pragma unroll
    for (int j = 0; j < 4; ++j) {
      float ls = __shfl(lsum, hi * 4 + j);
      inv[j] = 1.0f / ls;
    }
#pragma unroll
    for (int nd = 0; nd < 8; ++nd)
#pragma unroll
      for (int j = 0; j < 4; ++j) {
        int qr = qbase + hi * 4 + j;
        Og[((size_t)(b * S_LEN + qr) * NH + h) * DHD + nd * 16 + lr] = f2bf(of[nd][j] * inv[j]);
      }
  }
}

// ---------------- launch ----------------
extern "C" void kernel_launch(void* const* d_in, const int* in_sizes, int n_in,
                              void* d_out, int out_size, void* d_ws, size_t ws_size,
                              hipStream_t stream) {
  const float* x  = (const float*)d_in[0];
  const float* wq = (const float*)d_in[1];
  const float* wk = (const float*)d_in[2];
  const float* wv = (const float*)d_in[3];
  const float* wo = (const float*)d_in[4];
  float* out = (float*)d_out;

  char* ws = (char*)d_ws;
  unsigned short* xb    = (unsigned short*)(ws);              // 16 MB (reused as attn out)
  unsigned short* wqT   = (unsigned short*)(ws + 16777216);   // 8 MB each, contiguous -> [6144][2048]
  unsigned short* woT   = (unsigned short*)(ws + 41943040);
  unsigned short* qb    = (unsigned short*)(ws + 50331648);   // 16 MB each
  unsigned short* kb    = (unsigned short*)(ws + 67108864);
  unsigned short* vb    = (unsigned short*)(ws + 83886080);
  float*          cosT  = (float*)(ws + 100663296);           // 512 KB
  float*          sinT  = (float*)(ws + 101187584);
  unsigned short* attnb = xb;

  k_cast_bf16<<<8192, 256, 0, stream>>>(x, xb, 2097152);
  dim3 tg(32, 32, 4);
  k_transpose_all<<<tg, 256, 0, stream>>>(wq, wk, wv, wo, wqT);
  k_rope_table<<<512, 256, 0, stream>>>(cosT, sinT);

  // fused q/k/v projection: 32x24 tiles of 128x256 -> 768 blocks (3 even rounds)
  k_gemm128<1><<<768, 512, 0, stream>>>(xb, wqT, nullptr, qb, kb, vb, cosT, sinT, 6);

  dim3 ga(16, 16, 2);  // q-tile pairs, heads, batch
  k_flash_attn<<<ga, 256, 0, stream>>>(qb, kb, vb, attnb);

  // output projection: 32x8 tiles -> 256 blocks (1 round)
  k_gemm128<0><<<256, 512, 0, stream>>>(attnb, woT, out, nullptr, nullptr, nullptr,
                                        nullptr, nullptr, 2);
}